// Round 7
// baseline (265.249 us; speedup 1.0000x reference)
//
#include <hip/hip_runtime.h>
#include <hip/hip_bf16.h>

typedef __hip_bfloat16 bf16;
typedef __attribute__((ext_vector_type(8))) short short8;
typedef __attribute__((ext_vector_type(4))) float f32x4;
typedef __attribute__((ext_vector_type(16))) float f32x16;
#define MFMA16(a, b, c) __builtin_amdgcn_mfma_f32_16x16x32_bf16(a, b, c, 0, 0, 0)
#define MFMA32(a, b, c) __builtin_amdgcn_mfma_f32_32x32x16_bf16(a, b, c, 0, 0, 0)

#define BB   16
#define CCH  512
#define NN   1024
#define LLT  77
#define LPAD 128
#define NHH  8
#define HDD  64
#define GGN  32
#define NKV  1101   /* 1024 + 77 */
#define KVP  1152   /* 18 * 64, padded KV rows */

__device__ __forceinline__ unsigned short f2bu(float f){
  bf16 h = __float2bfloat16(f);
  return *reinterpret_cast<unsigned short*>(&h);
}

// single-instruction packed f32->bf16 (RNE)
__device__ __forceinline__ unsigned pk2(float lo, float hi){
  unsigned r;
  asm("v_cvt_pk_bf16_f32 %0, %1, %2" : "=v"(r) : "v"(lo), "v"(hi));
  return r;
}

// raw v_exp_f32 (exp2)
__device__ __forceinline__ float fexp2(float x){
  float r;
  asm("v_exp_f32 %0, %1" : "=v"(r) : "v"(x));
  return r;
}

// v_permlane32_swap_b32: new_a = {a.lo, b.lo}, new_b = {a.hi, b.hi}
__device__ __forceinline__ void pl32swap(unsigned &a, unsigned &b){
  asm("v_permlane32_swap_b32 %0, %1" : "+v"(a), "+v"(b));
}

// async global->LDS DMA, 16B per lane: lds dest = uniform base + lane*16,
// global src is per-lane.
__device__ __forceinline__ void gload16(const bf16* g, bf16* l){
  __builtin_amdgcn_global_load_lds(
      (const __attribute__((address_space(1))) unsigned int*)g,
      (__attribute__((address_space(3))) unsigned int*)l,
      16, 0, 0);
}

// --------------------- fused GN stats (1024 blocks) + weight prep (384) -----
__global__ __launch_bounds__(256) void pre_kernel(
    const float* __restrict__ ximg, const float* __restrict__ xtxt,
    float* __restrict__ stats,
    const float* __restrict__ W0, const float* __restrict__ W1,
    const float* __restrict__ W2, const float* __restrict__ W3,
    const float* __restrict__ W4, const float* __restrict__ W5,
    bf16* __restrict__ Wt)
{
  __shared__ float sh1[256], sh2[256];
  __shared__ alignas(16) float Ws[64][68];

  if (blockIdx.x < 1024){
    int isimg = blockIdx.x < 512;
    int bid = blockIdx.x & 511;
    int b = bid >> 5, g = bid & 31;
    int npos = isimg ? NN : LLT;
    const float* xb = (isimg ? ximg : xtxt) + (size_t)b * npos * CCH + g * 16;
    int tot4 = npos * 4;
    float s = 0.f, s2 = 0.f;
    for (int e = threadIdx.x; e < tot4; e += 256){
      int n = e >> 2, cq = (e & 3) * 4;
      float4 v = *(const float4*)(xb + (size_t)n * CCH + cq);
      s  += v.x + v.y + v.z + v.w;
      s2 += v.x * v.x + v.y * v.y + v.z * v.z + v.w * v.w;
    }
    sh1[threadIdx.x] = s; sh2[threadIdx.x] = s2;
    __syncthreads();
    for (int off = 128; off > 0; off >>= 1){
      if (threadIdx.x < off){
        sh1[threadIdx.x] += sh1[threadIdx.x + off];
        sh2[threadIdx.x] += sh2[threadIdx.x + off];
      }
      __syncthreads();
    }
    if (threadIdx.x == 0){
      float inv = 1.f / (float)(npos * 16);
      float m = sh1[0] * inv;
      float var = sh2[0] * inv - m * m;
      float* mu = stats + (isimg ? 0 : 1024);
      mu[bid] = m;
      mu[512 + bid] = rsqrtf(var + 1e-6f);
    }
  } else {
    int i = blockIdx.x - 1024;           // 0..383
    int wsel = i >> 6;                   // 0..5
    int rem  = i & 63;
    int n0 = (rem & 7) * 64, k0 = (rem >> 3) * 64;
    const float* W = wsel == 0 ? W0 : wsel == 1 ? W1 : wsel == 2 ? W2 :
                     wsel == 3 ? W3 : wsel == 4 ? W4 : W5;
    bf16* dst = Wt + (size_t)wsel * CCH * CCH;

    int r = threadIdx.x >> 2, c = (threadIdx.x & 3) * 16;
    const float* src = W + (size_t)(k0 + r) * CCH + n0 + c;
    *(float4*)&Ws[r][c]      = *(const float4*)(src);
    *(float4*)&Ws[r][c + 4]  = *(const float4*)(src + 4);
    *(float4*)&Ws[r][c + 8]  = *(const float4*)(src + 8);
    *(float4*)&Ws[r][c + 12] = *(const float4*)(src + 12);
    __syncthreads();

    int nr = threadIdx.x >> 2, kc = (threadIdx.x & 3) * 16;
    uint4 o0, o1;
    o0.x = pk2(Ws[kc + 0][nr],  Ws[kc + 1][nr]);
    o0.y = pk2(Ws[kc + 2][nr],  Ws[kc + 3][nr]);
    o0.z = pk2(Ws[kc + 4][nr],  Ws[kc + 5][nr]);
    o0.w = pk2(Ws[kc + 6][nr],  Ws[kc + 7][nr]);
    o1.x = pk2(Ws[kc + 8][nr],  Ws[kc + 9][nr]);
    o1.y = pk2(Ws[kc + 10][nr], Ws[kc + 11][nr]);
    o1.z = pk2(Ws[kc + 12][nr], Ws[kc + 13][nr]);
    o1.w = pk2(Ws[kc + 14][nr], Ws[kc + 15][nr]);
    bf16* d = dst + (size_t)(n0 + nr) * CCH + k0 + kc;
    *(uint4*)d = o0;
    *(uint4*)(d + 8) = o1;
  }
}

// ------------------------------------------------- norm img+text fused -> bf16
// Q side is pre-scaled by (1/sqrt(64)) * log2(e) so attention can use exp2.
__global__ __launch_bounds__(256) void norm_all_kernel(
    const float* __restrict__ x, const float* __restrict__ t,
    const float* __restrict__ stats,
    const float* __restrict__ gqs, const float* __restrict__ gqb,
    const float* __restrict__ gks, const float* __restrict__ gkb,
    const float* __restrict__ gts, const float* __restrict__ gtb,
    bf16* __restrict__ Xq, bf16* __restrict__ Xkv, bf16* __restrict__ Tn)
{
  if (blockIdx.x < 4096){
    size_t e = ((size_t)blockIdx.x * 256 + threadIdx.x) * 8;
    int b  = (int)(e >> 19);
    int ch = (int)(e & 511);
    int g  = ch >> 4;
    float m = stats[b * GGN + g], r = stats[512 + b * GGN + g];
    float4 x0 = *(const float4*)(x + e);
    float4 x1 = *(const float4*)(x + e + 4);
    float4 sq0 = *(const float4*)(gqs + ch), sq1 = *(const float4*)(gqs + ch + 4);
    float4 bq0 = *(const float4*)(gqb + ch), bq1 = *(const float4*)(gqb + ch + 4);
    float4 sk0 = *(const float4*)(gks + ch), sk1 = *(const float4*)(gks + ch + 4);
    float4 bk0 = *(const float4*)(gkb + ch), bk1 = *(const float4*)(gkb + ch + 4);
    float xs[8] = {x0.x,x0.y,x0.z,x0.w,x1.x,x1.y,x1.z,x1.w};
    float sqv[8] = {sq0.x,sq0.y,sq0.z,sq0.w,sq1.x,sq1.y,sq1.z,sq1.w};
    float bqv[8] = {bq0.x,bq0.y,bq0.z,bq0.w,bq1.x,bq1.y,bq1.z,bq1.w};
    float skv[8] = {sk0.x,sk0.y,sk0.z,sk0.w,sk1.x,sk1.y,sk1.z,sk1.w};
    float bkv[8] = {bk0.x,bk0.y,bk0.z,bk0.w,bk1.x,bk1.y,bk1.z,bk1.w};
    float q[8], k[8];
    #pragma unroll
    for (int j = 0; j < 8; j++){
      float nx = (xs[j] - m) * r;
      q[j] = (nx * sqv[j] + bqv[j]) * 0.18033688f; /* 0.125*log2(e) */
      k[j] = nx * skv[j] + bkv[j];
    }
    uint4 oq, ok;
    oq.x = pk2(q[0], q[1]); oq.y = pk2(q[2], q[3]);
    oq.z = pk2(q[4], q[5]); oq.w = pk2(q[6], q[7]);
    ok.x = pk2(k[0], k[1]); ok.y = pk2(k[2], k[3]);
    ok.z = pk2(k[4], k[5]); ok.w = pk2(k[6], k[7]);
    *(uint4*)(Xq + e)  = oq;
    *(uint4*)(Xkv + e) = ok;
  } else {
    size_t e = ((size_t)(blockIdx.x - 4096) * 256 + threadIdx.x) * 8;
    int b  = (int)(e >> 16);
    int rem = (int)(e & 65535);
    int l  = rem >> 9;
    int ch = rem & 511;
    uint4 o;
    if (l < LLT){
      int g = ch >> 4;
      float m = stats[1024 + b * GGN + g], r = stats[1536 + b * GGN + g];
      const float* src = t + ((size_t)b * LLT + l) * CCH + ch;
      float4 x0 = *(const float4*)src, x1 = *(const float4*)(src + 4);
      float4 s0 = *(const float4*)(gts + ch), s1 = *(const float4*)(gts + ch + 4);
      float4 b0 = *(const float4*)(gtb + ch), b1 = *(const float4*)(gtb + ch + 4);
      float xs[8] = {x0.x,x0.y,x0.z,x0.w,x1.x,x1.y,x1.z,x1.w};
      float sv[8] = {s0.x,s0.y,s0.z,s0.w,s1.x,s1.y,s1.z,s1.w};
      float bv[8] = {b0.x,b0.y,b0.z,b0.w,b1.x,b1.y,b1.z,b1.w};
      float w[8];
      #pragma unroll
      for (int j = 0; j < 8; j++) w[j] = (xs[j] - m) * r * sv[j] + bv[j];
      o.x = pk2(w[0], w[1]); o.y = pk2(w[2], w[3]);
      o.z = pk2(w[4], w[5]); o.w = pk2(w[6], w[7]);
    } else {
      o = make_uint4(0, 0, 0, 0);
    }
    *(uint4*)(Tn + e) = o;
  }
}

// -------- fused projections ---------------------------------------------
// blocks 0-511:    Q  (128x128 tile, 4 staged tiles/K-step, gload_lds)
// blocks 512-1023: K+V fused (shared A_kv stage: 6 tiles for TWO 128x128
//                  outputs -> -25% staging vs separate K and V blocks)
// blocks 1024-1279: cross KV (reg-staged, small)
// rt-fastest decode keeps blocks sharing an A-panel on the same XCD.
// Q/K epilogues go through a per-wave LDS transpose -> 8 vectorized stores
// per thread instead of 64 scalar 2B stores.
__global__ __launch_bounds__(256) void proj_all_mfma(
    const bf16* __restrict__ Xq, const bf16* __restrict__ Xkv,
    const bf16* __restrict__ Tn, const bf16* __restrict__ Wt,
    bf16* __restrict__ Qo, bf16* __restrict__ Ko, bf16* __restrict__ Vo)
{
  __shared__ alignas(16) char SHRAW[49152];
  const int tid  = threadIdx.x;
  const int wave = tid >> 6, lane = tid & 63;
  const int l16 = lane & 15, quad = lane >> 4;
  const int bx = blockIdx.x;
  const int lrow = lane >> 3, lcol = (lane & 7) * 8;

  if (bx < 512){
    // ------------------------------ Q projection
    bf16 (*T)[64][64] = reinterpret_cast<bf16(*)[64][64]>(SHRAW);
    const int wr = wave >> 1, wc = wave & 1;
    const int ct = bx >> 7;             // 0..3
    const int rt = bx & 127;
    const int cm0 = ct * 128;
    const int b  = rt >> 3;
    const int n0 = (rt & 7) * 128;

    const bf16* Bw = Wt + (size_t)cm0 * CCH;

    f32x4 acc[4][4];
    #pragma unroll
    for (int rf = 0; rf < 4; rf++)
      #pragma unroll
      for (int cf = 0; cf < 4; cf++) acc[rf][cf] = (f32x4){0.f,0.f,0.f,0.f};

    const bf16* srcbase = (wave < 2)
        ? Xq + ((size_t)b * NN + n0 + wave * 64) * CCH
        : Bw + (size_t)((wave - 2) * 64) * CCH;

    for (int kt = 0; kt < 8; kt++){
      const int kc = kt * 64;
      #pragma unroll
      for (int c = 0; c < 8; c++){
        const bf16* g = srcbase + (size_t)(c * 8 + lrow) * CCH + kc + lcol;
        gload16(g, &T[wave][c * 8][0]);
      }
      __syncthreads();

      short8 af[4][2];
      #pragma unroll
      for (int rf = 0; rf < 4; rf++){
        af[rf][0] = *(const short8*)&T[wr][rf * 16 + l16][quad * 8];
        af[rf][1] = *(const short8*)&T[wr][rf * 16 + l16][32 + quad * 8];
      }
      #pragma unroll
      for (int cf = 0; cf < 4; cf++){
        const short8 b0 = *(const short8*)&T[2 + wc][cf * 16 + l16][quad * 8];
        const short8 b1 = *(const short8*)&T[2 + wc][cf * 16 + l16][32 + quad * 8];
        #pragma unroll
        for (int rf = 0; rf < 4; rf++){
          acc[rf][cf] = MFMA16(af[rf][0], b0, acc[rf][cf]);
          acc[rf][cf] = MFMA16(af[rf][1], b1, acc[rf][cf]);
        }
      }
      __syncthreads();
    }

    // epilogue: per-wave transpose (rows n, cols d) then coalesced rows
    bf16 (*Tw)[64] = T[wave];
    #pragma unroll
    for (int rf = 0; rf < 4; rf++)
      #pragma unroll
      for (int cf = 0; cf < 4; cf++)
        #pragma unroll
        for (int r = 0; r < 4; r++)
          Tw[rf * 16 + quad * 4 + r][cf * 16 + l16] =
              __float2bfloat16(acc[rf][cf][r]);
    const int h  = (cm0 + wc * 64) >> 6;
    const int nb = n0 + wr * 64;
    const int rr = lane >> 2, cs = (lane & 3) * 16;
    #pragma unroll
    for (int k2 = 0; k2 < 4; k2++){
      const int row = rr + k2 * 16;
      bf16* qd = Qo + (((size_t)b * NHH + h) * NN + nb + row) * HDD + cs;
      *(uint4*)qd       = *(const uint4*)&Tw[row][cs];
      *(uint4*)(qd + 8) = *(const uint4*)&Tw[row][cs + 8];
    }
  } else if (bx < 1024){
    // ------------------------------ K+V fused (shared A_kv stage)
    bf16 (*T)[64][64] = reinterpret_cast<bf16(*)[64][64]>(SHRAW);
    const int wr = wave >> 1, wc = wave & 1;
    const int ct = (bx - 512) >> 7;     // 0..3
    const int rt = bx & 127;
    const int cm0 = ct * 128;
    const int b  = rt >> 3;
    const int n0 = (rt & 7) * 128;

    const bf16* Bk_ = Wt + 1 * (size_t)CCH * CCH + (size_t)cm0 * CCH;
    const bf16* Bv_ = Wt + 2 * (size_t)CCH * CCH + (size_t)cm0 * CCH;

    f32x4 aK[4][4], aV[4][4];
    #pragma unroll
    for (int rf = 0; rf < 4; rf++)
      #pragma unroll
      for (int cf = 0; cf < 4; cf++){
        aK[rf][cf] = (f32x4){0.f,0.f,0.f,0.f};
        aV[rf][cf] = (f32x4){0.f,0.f,0.f,0.f};
      }

    for (int kt = 0; kt < 8; kt++){
      const int kc = kt * 64;
      // 6 tiles x 8 chunks = 48 issues; wave w does [12w, 12w+12)
      #pragma unroll
      for (int j = 0; j < 12; j++){
        const int i = wave * 12 + j;
        const int tile = i >> 3, ch = i & 7;
        const bf16* base;
        if (tile < 2)      base = Xkv + ((size_t)b * NN + n0 + tile * 64) * CCH;
        else if (tile < 4) base = Bk_ + (size_t)((tile - 2) * 64) * CCH;
        else               base = Bv_ + (size_t)((tile - 4) * 64) * CCH;
        const bf16* g = base + (size_t)(ch * 8 + lrow) * CCH + kc + lcol;
        gload16(g, &T[tile][ch * 8][0]);
      }
      __syncthreads();

      short8 af[4][2];
      #pragma unroll
      for (int rf = 0; rf < 4; rf++){
        af[rf][0] = *(const short8*)&T[wr][rf * 16 + l16][quad * 8];
        af[rf][1] = *(const short8*)&T[wr][rf * 16 + l16][32 + quad * 8];
      }
      #pragma unroll
      for (int cf = 0; cf < 4; cf++){
        const short8 bk0 = *(const short8*)&T[2 + wc][cf * 16 + l16][quad * 8];
        const short8 bk1 = *(const short8*)&T[2 + wc][cf * 16 + l16][32 + quad * 8];
        #pragma unroll
        for (int rf = 0; rf < 4; rf++){
          aK[rf][cf] = MFMA16(af[rf][0], bk0, aK[rf][cf]);
          aK[rf][cf] = MFMA16(af[rf][1], bk1, aK[rf][cf]);
        }
        const short8 bv0 = *(const short8*)&T[4 + wc][cf * 16 + l16][quad * 8];
        const short8 bv1 = *(const short8*)&T[4 + wc][cf * 16 + l16][32 + quad * 8];
        #pragma unroll
        for (int rf = 0; rf < 4; rf++){
          aV[rf][cf] = MFMA16(af[rf][0], bv0, aV[rf][cf]);
          aV[rf][cf] = MFMA16(af[rf][1], bv1, aV[rf][cf]);
        }
      }
      __syncthreads();
    }

    const int h  = (cm0 + wc * 64) >> 6;
    const int nb = n0 + wr * 64;
    bf16 (*Tw)[64] = T[wave];

    // K epilogue: transpose (rows n, cols d), coalesced rows
    #pragma unroll
    for (int rf = 0; rf < 4; rf++)
      #pragma unroll
      for (int cf = 0; cf < 4; cf++)
        #pragma unroll
        for (int r = 0; r < 4; r++)
          Tw[rf * 16 + quad * 4 + r][cf * 16 + l16] =
              __float2bfloat16(aK[rf][cf][r]);
    {
      const int rr = lane >> 2, cs = (lane & 3) * 16;
      #pragma unroll
      for (int k2 = 0; k2 < 4; k2++){
        const int row = rr + k2 * 16;
        bf16* kd = Ko + (((size_t)b * NHH + h) * KVP + nb + row) * HDD + cs;
        *(uint4*)kd       = *(const uint4*)&Tw[row][cs];
        *(uint4*)(kd + 8) = *(const uint4*)&Tw[row][cs + 8];
      }
    }
    __syncthreads();   // safety: K reads done before V overwrites

    // V epilogue: transpose (rows d, cols n), coalesced d-rows of Vt
    #pragma unroll
    for (int cf = 0; cf < 4; cf++)
      #pragma unroll
      for (int rf = 0; rf < 4; rf++)
        #pragma unroll
        for (int r = 0; r < 4; r++)
          Tw[cf * 16 + l16][rf * 16 + quad * 4 + r] =
              __float2bfloat16(aV[rf][cf][r]);
    __syncthreads();
    {
      const int dl = lane >> 2, cseg = (lane & 3) * 16;
      #pragma unroll
      for (int k2 = 0; k2 < 4; k2++){
        const int d = dl + k2 * 16;
        bf16* vd = Vo + (((size_t)b * NHH + h) * HDD + d) * KVP + nb + cseg;
        *(uint4*)vd       = *(const uint4*)&Tw[d][cseg];
        *(uint4*)(vd + 8) = *(const uint4*)&Tw[d][cseg + 8];
      }
    }
  } else {
    // ------------------------------ cross KV (reg-staged, small)
    bf16 (*At)[72] = reinterpret_cast<bf16(*)[72]>(SHRAW);
    bf16 (*Bk)[72] = reinterpret_cast<bf16(*)[72]>(SHRAW + 64 * 72 * 2);
    bf16 (*Bv)[72] = reinterpret_cast<bf16(*)[72]>(SHRAW + 2 * 64 * 72 * 2);
    const int i  = bx - 1024;           // 0..255
    const int h  = i & 7;
    const int l0 = ((i >> 3) & 1) * 64;
    const int b  = i >> 4;

    const bf16* Wkc = Wt + 3 * (size_t)CCH * CCH;
    const bf16* Wvc = Wt + 4 * (size_t)CCH * CCH;

    f32x4 sk[4], sv[4];
    #pragma unroll
    for (int nt = 0; nt < 4; nt++){
      sk[nt] = (f32x4){0.f,0.f,0.f,0.f};
      sv[nt] = (f32x4){0.f,0.f,0.f,0.f};
    }

    const int sr = tid >> 2, sc = (tid & 3) * 16;
    const bf16* p_a  = Tn  + ((size_t)b * LPAD + l0 + sr) * CCH + sc;
    const bf16* p_bk = Wkc + (size_t)(h * 64 + sr) * CCH + sc;
    const bf16* p_bv = Wvc + (size_t)(h * 64 + sr) * CCH + sc;

    uint4 ra0 = *(const uint4*)p_a,   ra1 = *(const uint4*)(p_a + 8);
    uint4 rk0 = *(const uint4*)p_bk,  rk1 = *(const uint4*)(p_bk + 8);
    uint4 rv0 = *(const uint4*)p_bv,  rv1 = *(const uint4*)(p_bv + 8);

    for (int kt = 0; kt < 8; kt++){
      *(uint4*)&At[sr][sc]     = ra0;  *(uint4*)&At[sr][sc + 8] = ra1;
      *(uint4*)&Bk[sr][sc]     = rk0;  *(uint4*)&Bk[sr][sc + 8] = rk1;
      *(uint4*)&Bv[sr][sc]     = rv0;  *(uint4*)&Bv[sr][sc + 8] = rv1;
      if (kt < 7){
        const int k1 = (kt + 1) * 64;
        ra0 = *(const uint4*)(p_a + k1);   ra1 = *(const uint4*)(p_a + k1 + 8);
        rk0 = *(const uint4*)(p_bk + k1);  rk1 = *(const uint4*)(p_bk + k1 + 8);
        rv0 = *(const uint4*)(p_bv + k1);  rv1 = *(const uint4*)(p_bv + k1 + 8);
      }
      __syncthreads();

      const short8 a0 = *(const short8*)&At[wave * 16 + l16][quad * 8];
      const short8 a1 = *(const short8*)&At[wave * 16 + l16][32 + quad * 8];
      #pragma unroll
      for (int nt = 0; nt < 4; nt++){
        const short8 bk0 = *(const short8*)&Bk[nt * 16 + l16][quad * 8];
        const short8 bk1 = *(const short8*)&Bk[nt * 16 + l16][32 + quad * 8];
        sk[nt] = MFMA16(a0, bk0, sk[nt]);
        sk[nt] = MFMA16(a1, bk1, sk[nt]);
        const short8 bv0 = *(const short8*)&Bv[nt * 16 + l16][quad * 8];
        const short8 bv1 = *(const short8*)&Bv[nt * 16 + l16][32 + quad * 8];
        sv[nt] = MFMA16(a0, bv0, sv[nt]);
        sv[nt] = MFMA16(a1, bv1, sv[nt]);
      }
      __syncthreads();
    }

    #pragma unroll
    for (int r = 0; r < 4; r++){
      int kvrow = NN + l0 + wave * 16 + quad * 4 + r;
      bf16* kd = Ko + (((size_t)b * NHH + h) * KVP + kvrow) * HDD + l16;
      #pragma unroll
      for (int nt = 0; nt < 4; nt++)
        kd[nt * 16] = __float2bfloat16(sk[nt][r]);
    }

    __syncthreads();
    #pragma unroll
    for (int nt = 0; nt < 4; nt++)
      #pragma unroll
      for (int r = 0; r < 4; r++)
        Bk[nt * 16 + l16][wave * 16 + quad * 4 + r] = __float2bfloat16(sv[nt][r]);
    __syncthreads();
    {
      int d = tid >> 2, c = (tid & 3) * 16;
      bf16* vd = Vo + (((size_t)b * NHH + h) * HDD + d) * KVP + NN + l0 + c;
      *(uint4*)vd       = *(const uint4*)&Bk[d][c];
      *(uint4*)(vd + 8) = *(const uint4*)&Bk[d][c + 8];
    }
  }
}

// ------- MFMA flash attention, 32x32x16 path (UNCHANGED — control) ----------
__global__ __launch_bounds__(256, 4) void attn_mfma_kernel(
    const bf16* __restrict__ Q, const bf16* __restrict__ K,
    const bf16* __restrict__ Vt, const int* __restrict__ tmask,
    bf16* __restrict__ Ao)
{
  const int tid  = threadIdx.x;
  const int wave = tid >> 6;
  const int lane = tid & 63;
  const int l31  = lane & 31;
  const int hi   = lane >> 5;
  const int bx = blockIdx.x;
  const int q0 = (bx >> 7) * 128;
  const int g  = bx & 127;
  const int h  = g & 7;
  const int b  = g >> 3;

  __shared__ alignas(16) bf16 KV[2][2][64][72];

  const bf16* qp = Q + (((size_t)b * NHH + h) * NN + q0 + wave * 32 + l31) * HDD + hi * 8;
  short8 qf[4];
  qf[0] = *(const short8*)(qp);
  qf[1] = *(const short8*)(qp + 16);
  qf[2] = *(const short8*)(qp + 32);
  qf[3] = *(const short8*)(qp + 48);

  union { unsigned u[4]; short8 s8; } ones;
  ones.u[0] = 0x3F803F80u; ones.u[1] = 0x3F803F80u;
  ones.u[2] = 0x3F803F80u; ones.u[3] = 0x3F803F80u;

  f32x16 zf;
  #pragma unroll
  for (int i = 0; i < 16; i++) zf[i] = 0.f;

  f32x16 o_acc[2], l_acc;
  #pragma unroll
  for (int dt = 0; dt < 2; dt++)
    #pragma unroll
    for (int i = 0; i < 16; i++) o_acc[dt][i] = 0.f;
  #pragma unroll
  for (int i = 0; i < 16; i++) l_acc[i] = 0.f;

  const size_t kbase = ((size_t)b * NHH + h) * KVP;
  const size_t vbase = ((size_t)b * NHH + h) * (size_t)HDD * KVP;

  const int sr = tid >> 2;
  const int sc = (tid & 3) * 16;
  const bf16* kp = K  + (kbase + sr) * HDD + sc;
  const bf16* vp = Vt + vbase + (size_t)sr * KVP + sc;

  uint4 kr0 = *(const uint4*)kp, kr1 = *(const uint4*)(kp + 8);
  uint4 vr0 = *(const uint4*)vp, vr1 = *(const uint4*)(vp + 8);
  *(uint4*)&KV[0][0][sr][sc]     = kr0;
  *(uint4*)&KV[0][0][sr][sc + 8] = kr1;
  *(uint4*)&KV[0][1][sr][sc]     = vr0;
  *(uint4*)&KV[0][1][sr][sc + 8] = vr1;
  kr0 = *(const uint4*)(kp + 4096); kr1 = *(const uint4*)(kp + 4096 + 8);
  vr0 = *(const uint4*)(vp + 64);   vr1 = *(const uint4*)(vp + 64 + 8);
  __syncthreads();

  for (int kt = 0; kt < 18; kt++){
    const int cur = kt & 1;
    if (kt + 1 < 18){
      *(uint4*)&KV[cur ^ 1][0][sr][sc]     = kr0;
      *(uint4*)&KV[cur ^ 1][0][sr][sc + 8] = kr1;
      *(uint4*)&KV[cur ^ 1][1][sr][sc]     = vr0;
      *(uint4*)&KV[cur ^ 1][1][sr][sc + 8] = vr1;
    }
    if (kt + 2 < 18){
      const size_t ko = (size_t)(kt + 2) * 4096;
      const int    vo = (kt + 2) * 64;
      kr0 = *(const uint4*)(kp + ko); kr1 = *(const uint4*)(kp + ko + 8);
      vr0 = *(const uint4*)(vp + vo); vr1 = *(const uint4*)(vp + vo + 8);
    }

    const bf16 (*Ks)[72] = KV[cur][0];
    const bf16 (*Vs)[72] = KV[cur][1];
    const int kv0 = kt * 64;

    #pragma unroll
    for (int t = 0; t < 2; t++){
      const short8 kf0 = *(const short8*)&Ks[t * 32 + l31][hi * 8];
      const short8 kf1 = *(const short8*)&Ks[t * 32 + l31][16 + hi * 8];
      const short8 kf2 = *(const short8*)&Ks[t * 32 + l31][32 + hi * 8];
      const short8 kf3 = *(const short8*)&Ks[t * 32 + l31][48 + hi * 8];
      __builtin_amdgcn_s_setprio(1);
      f32x16 s = MFMA32(kf0, qf[0], zf);
      s = MFMA32(kf1, qf[1], s);
      s = MFMA32(kf2, qf[2], s);
      s = MFMA32(kf3, qf[3], s);
      __builtin_amdgcn_s_setprio(0);

      if (kv0 + 64 > NN){  // boundary tiles: text mask + KV padding
        #pragma unroll
        for (int r = 0; r < 16; r++){
          int idx = kv0 - NN + t * 32 + (r & 3) + 8 * (r >> 2) + 4 * hi;
          int ci = idx < LLT ? idx : LLT - 1;
          float rep = (idx < LLT)
                        ? (tmask[b * LLT + ci] > 0 ? 1e30f : -1e10f)
                        : -1e30f;
          s[r] = fminf(s[r], rep);
        }
      }

      #pragma unroll
      for (int r = 0; r < 16; r++) s[r] = fexp2(s[r]);

      unsigned w0 = pk2(s[0],  s[1]),  w1 = pk2(s[2],  s[3]);
      unsigned w2 = pk2(s[4],  s[5]),  w3 = pk2(s[6],  s[7]);
      unsigned w4 = pk2(s[8],  s[9]),  w5 = pk2(s[10], s[11]);
      unsigned w6 = pk2(s[12], s[13]), w7 = pk2(s[14], s[15]);
      pl32swap(w0, w2);
      pl32swap(w1, w3);
      pl32swap(w4, w6);
      pl32swap(w5, w7);
      union { unsigned u[4]; short8 s8; } pf0, pf1;
      pf0.u[0] = w0; pf0.u[1] = w1; pf0.u[2] = w2; pf0.u[3] = w3;
      pf1.u[0] = w4; pf1.u[1] = w5; pf1.u[2] = w6; pf1.u[3] = w7;

      const short8 vf00 = *(const short8*)&Vs[l31][t * 32 + hi * 8];
      const short8 vf01 = *(const short8*)&Vs[l31][t * 32 + 16 + hi * 8];
      const short8 vf10 = *(const short8*)&Vs[32 + l31][t * 32 + hi * 8];
      const short8 vf11 = *(const short8*)&Vs[32 + l31][t * 32 + 16 + hi * 8];

      __builtin_amdgcn_s_setprio(1);
      l_acc = MFMA32(pf0.s8, ones.s8, l_acc);
      l_acc = MFMA32(pf1.s8, ones.s8, l_acc);
      o_acc[0] = MFMA32(pf0.s8, vf00, o_acc[0]);
      o_acc[0] = MFMA32(pf1.s8, vf01, o_acc[0]);
      o_acc[1] = MFMA32(pf0.s8, vf10, o_acc[1]);
      o_acc[1] = MFMA32(pf1.s8, vf11, o_acc[1]);
      __builtin_amdgcn_s_setprio(0);
    }
    __syncthreads();
  }

  #pragma unroll
  for (int r = 0; r < 16; r++){
    const int ql = (r & 3) + 8 * (r >> 2) + 4 * hi;
    const float linv = 1.f / l_acc[r];
    const int n = q0 + wave * 32 + ql;
    bf16* dst = Ao + ((size_t)b * NN + n) * CCH + h * HDD + l31;
    dst[0]  = __float2bfloat16(o_acc[0][r] * linv);
    dst[32] = __float2bfloat16(o_acc[1][r] * linv);
  }
}

// ------------- output proj + residual, gload_lds-staged 128x128 GEMM --------
__global__ __launch_bounds__(256) void outproj_mfma(
    const bf16* __restrict__ A, const bf16* __restrict__ Wt,
    const float* __restrict__ resid, float* __restrict__ out)
{
  __shared__ alignas(16) bf16 T[4][64][64];
  const int tid  = threadIdx.x;
  const int wave = tid >> 6, lane = tid & 63;
  const int l16 = lane & 15, quad = lane >> 4;
  const int wr = wave >> 1, wc = wave & 1;
  const int bx = blockIdx.x;
  const int c0 = (bx >> 7) * 128;     // 0..511
  const int g0 = (bx & 127) * 128;    // 0..16383

  const bf16* Bw = Wt + (size_t)5 * CCH * CCH + (size_t)c0 * CCH;

  f32x4 acc[4][4];
  #pragma unroll
  for (int rf = 0; rf < 4; rf++)
    #pragma unroll
    for (int cf = 0; cf < 4; cf++) acc[rf][cf] = (f32x4){0.f,0.f,0.f,0.f};

  const int lrow = lane >> 3, lcol = (lane & 7) * 8;
  const bf16* srcbase = (wave < 2)
      ? A  + ((size_t)g0 + wave * 64) * CCH
      : Bw + (size_t)((wave - 2) * 64) * CCH;

  for (int kt = 0; kt < 8; kt++){
    const int kc = kt * 64;
    #pragma unroll
    for (int c = 0; c < 8; c++){
      const bf16* g = srcbase + (size_t)(c * 8 + lrow) * CCH + kc + lcol;
      gload16(g, &T[wave][c * 8][0]);
    }
    __syncthreads();

    short8 af[4][2];
    #pragma unroll
    for (int rf = 0; rf < 4; rf++){
      af[rf][0] = *(const short8*)&T[wr][rf * 16 + l16][quad * 8];
      af[rf][1] = *(const short8*)&T[wr][rf * 16 + l16][32 + quad * 8];
    }
    #pragma unroll
    for (int cf = 0; cf < 4; cf++){
      const short8 b0 = *(const short8*)&T[2 + wc][cf * 16 + l16][quad * 8];
      const short8 b1 = *(const short8*)&T[2 + wc][cf * 16 + l16][32 + quad * 8];
      #pragma unroll
      for (int rf = 0; rf < 4; rf++){
        acc[rf][cf] = MFMA16(af[rf][0], b0, acc[rf][cf]);
        acc[rf][cf] = MFMA16(af[rf][1], b1, acc[rf][cf]);
      }
    }
    __syncthreads();
  }

  #pragma unroll
  for (int rf = 0; rf < 4; rf++)
    #pragma unroll
    for (int r = 0; r < 4; r++){
      const size_t row = (size_t)g0 + wr * 64 + rf * 16 + quad * 4 + r;
      #pragma unroll
      for (int cf = 0; cf < 4; cf++){
        const int col = c0 + wc * 64 + cf * 16 + l16;
        out[row * CCH + col] = acc[rf][cf][r] + resid[row * CCH + col];
      }
    }
}

// --------------------------------------------------------------- launcher
extern "C" void kernel_launch(void* const* d_in, const int* in_sizes, int n_in,
                              void* d_out, int out_size, void* d_ws, size_t ws_size,
                              hipStream_t stream)
{
  const float* x     = (const float*)d_in[0];
  const float* txt   = (const float*)d_in[1];
  const int*   tmask = (const int*)d_in[2];
  const float* gqs   = (const float*)d_in[3];
  const float* gqb   = (const float*)d_in[4];
  const float* gks   = (const float*)d_in[5];
  const float* gkb   = (const float*)d_in[6];
  const float* gts   = (const float*)d_in[7];
  const float* gtb   = (const float*)d_in[8];
  const float* Wq    = (const float*)d_in[9];
  const float* Wks   = (const float*)d_in[10];
  const float* Wvs   = (const float*)d_in[11];
  const float* Wkc   = (const float*)d_in[12];
  const float* Wvc   = (const float*)d_in[13];
  const float* Wout  = (const float*)d_in[14];

  float* stats = (float*)d_ws;                            // 2048 floats
  bf16* WtAll = (bf16*)(stats + 2048);                    // 6 * 512 * 512
  bf16* Xq  = WtAll + (size_t)6 * CCH * CCH;
  bf16* Xkv = Xq  + (size_t)BB * NN * CCH;
  bf16* Tn  = Xkv + (size_t)BB * NN * CCH;
  bf16* Qw  = Tn  + (size_t)BB * LPAD * CCH;
  bf16* Kw  = Qw  + (size_t)BB * NHH * NN * HDD;
  bf16* Vw  = Kw  + (size_t)BB * NHH * KVP * HDD;         // [b,h,hd,kvp]
  bf16* Aw  = Xq;                                         // alias: Xq dead after proj

  pre_kernel<<<1408, 256, 0, stream>>>(
      x, txt, stats, Wq, Wks, Wvs, Wkc, Wvc, Wout, WtAll);
  norm_all_kernel<<<4608, 256, 0, stream>>>(
      x, txt, stats, gqs, gqb, gks, gkb, gts, gtb, Xq, Xkv, Tn);
  proj_all_mfma<<<1280, 256, 0, stream>>>(
      Xq, Xkv, Tn, WtAll, Qw, Kw, Vw);
  attn_mfma_kernel<<<1024, 256, 0, stream>>>(Qw, Kw, Vw, tmask, Aw);
  outproj_mfma<<<512, 256, 0, stream>>>(Aw, WtAll, x, (float*)d_out);
}

// Round 8
// 242.143 us; speedup vs baseline: 1.0954x; 1.0954x over previous
//
#include <hip/hip_runtime.h>
#include <hip/hip_bf16.h>

typedef __hip_bfloat16 bf16;
typedef __attribute__((ext_vector_type(8))) short short8;
typedef __attribute__((ext_vector_type(4))) float f32x4;
typedef __attribute__((ext_vector_type(16))) float f32x16;
#define MFMA16(a, b, c) __builtin_amdgcn_mfma_f32_16x16x32_bf16(a, b, c, 0, 0, 0)
#define MFMA32(a, b, c) __builtin_amdgcn_mfma_f32_32x32x16_bf16(a, b, c, 0, 0, 0)

#define BB   16
#define CCH  512
#define NN   1024
#define LLT  77
#define LPAD 128
#define NHH  8
#define HDD  64
#define GGN  32
#define NKV  1101   /* 1024 + 77 */
#define KVP  1152   /* 18 * 64, padded KV rows */

__device__ __forceinline__ unsigned short f2bu(float f){
  bf16 h = __float2bfloat16(f);
  return *reinterpret_cast<unsigned short*>(&h);
}

// single-instruction packed f32->bf16 (RNE)
__device__ __forceinline__ unsigned pk2(float lo, float hi){
  unsigned r;
  asm("v_cvt_pk_bf16_f32 %0, %1, %2" : "=v"(r) : "v"(lo), "v"(hi));
  return r;
}

// raw v_exp_f32 (exp2)
__device__ __forceinline__ float fexp2(float x){
  float r;
  asm("v_exp_f32 %0, %1" : "=v"(r) : "v"(x));
  return r;
}

// v_permlane32_swap_b32: new_a = {a.lo, b.lo}, new_b = {a.hi, b.hi}
__device__ __forceinline__ void pl32swap(unsigned &a, unsigned &b){
  asm("v_permlane32_swap_b32 %0, %1" : "+v"(a), "+v"(b));
}

// async global->LDS DMA, 16B per lane: lds dest = uniform base + lane*16,
// global src is per-lane.
__device__ __forceinline__ void gload16(const bf16* g, bf16* l){
  __builtin_amdgcn_global_load_lds(
      (const __attribute__((address_space(1))) unsigned int*)g,
      (__attribute__((address_space(3))) unsigned int*)l,
      16, 0, 0);
}

// --------------------- fused GN stats (1024 blocks) + weight prep (384) -----
__global__ __launch_bounds__(256) void pre_kernel(
    const float* __restrict__ ximg, const float* __restrict__ xtxt,
    float* __restrict__ stats,
    const float* __restrict__ W0, const float* __restrict__ W1,
    const float* __restrict__ W2, const float* __restrict__ W3,
    const float* __restrict__ W4, const float* __restrict__ W5,
    bf16* __restrict__ Wt)
{
  __shared__ float sh1[256], sh2[256];
  __shared__ alignas(16) float Ws[64][68];

  if (blockIdx.x < 1024){
    int isimg = blockIdx.x < 512;
    int bid = blockIdx.x & 511;
    int b = bid >> 5, g = bid & 31;
    int npos = isimg ? NN : LLT;
    const float* xb = (isimg ? ximg : xtxt) + (size_t)b * npos * CCH + g * 16;
    int tot4 = npos * 4;
    float s = 0.f, s2 = 0.f;
    for (int e = threadIdx.x; e < tot4; e += 256){
      int n = e >> 2, cq = (e & 3) * 4;
      float4 v = *(const float4*)(xb + (size_t)n * CCH + cq);
      s  += v.x + v.y + v.z + v.w;
      s2 += v.x * v.x + v.y * v.y + v.z * v.z + v.w * v.w;
    }
    sh1[threadIdx.x] = s; sh2[threadIdx.x] = s2;
    __syncthreads();
    for (int off = 128; off > 0; off >>= 1){
      if (threadIdx.x < off){
        sh1[threadIdx.x] += sh1[threadIdx.x + off];
        sh2[threadIdx.x] += sh2[threadIdx.x + off];
      }
      __syncthreads();
    }
    if (threadIdx.x == 0){
      float inv = 1.f / (float)(npos * 16);
      float m = sh1[0] * inv;
      float var = sh2[0] * inv - m * m;
      float* mu = stats + (isimg ? 0 : 1024);
      mu[bid] = m;
      mu[512 + bid] = rsqrtf(var + 1e-6f);
    }
  } else {
    int i = blockIdx.x - 1024;           // 0..383
    int wsel = i >> 6;                   // 0..5
    int rem  = i & 63;
    int n0 = (rem & 7) * 64, k0 = (rem >> 3) * 64;
    const float* W = wsel == 0 ? W0 : wsel == 1 ? W1 : wsel == 2 ? W2 :
                     wsel == 3 ? W3 : wsel == 4 ? W4 : W5;
    bf16* dst = Wt + (size_t)wsel * CCH * CCH;

    int r = threadIdx.x >> 2, c = (threadIdx.x & 3) * 16;
    const float* src = W + (size_t)(k0 + r) * CCH + n0 + c;
    *(float4*)&Ws[r][c]      = *(const float4*)(src);
    *(float4*)&Ws[r][c + 4]  = *(const float4*)(src + 4);
    *(float4*)&Ws[r][c + 8]  = *(const float4*)(src + 8);
    *(float4*)&Ws[r][c + 12] = *(const float4*)(src + 12);
    __syncthreads();

    int nr = threadIdx.x >> 2, kc = (threadIdx.x & 3) * 16;
    uint4 o0, o1;
    o0.x = pk2(Ws[kc + 0][nr],  Ws[kc + 1][nr]);
    o0.y = pk2(Ws[kc + 2][nr],  Ws[kc + 3][nr]);
    o0.z = pk2(Ws[kc + 4][nr],  Ws[kc + 5][nr]);
    o0.w = pk2(Ws[kc + 6][nr],  Ws[kc + 7][nr]);
    o1.x = pk2(Ws[kc + 8][nr],  Ws[kc + 9][nr]);
    o1.y = pk2(Ws[kc + 10][nr], Ws[kc + 11][nr]);
    o1.z = pk2(Ws[kc + 12][nr], Ws[kc + 13][nr]);
    o1.w = pk2(Ws[kc + 14][nr], Ws[kc + 15][nr]);
    bf16* d = dst + (size_t)(n0 + nr) * CCH + k0 + kc;
    *(uint4*)d = o0;
    *(uint4*)(d + 8) = o1;
  }
}

// ------------------------------------------------- norm img+text fused -> bf16
// Q side is pre-scaled by (1/sqrt(64)) * log2(e) so attention can use exp2.
__global__ __launch_bounds__(256) void norm_all_kernel(
    const float* __restrict__ x, const float* __restrict__ t,
    const float* __restrict__ stats,
    const float* __restrict__ gqs, const float* __restrict__ gqb,
    const float* __restrict__ gks, const float* __restrict__ gkb,
    const float* __restrict__ gts, const float* __restrict__ gtb,
    bf16* __restrict__ Xq, bf16* __restrict__ Xkv, bf16* __restrict__ Tn)
{
  if (blockIdx.x < 4096){
    size_t e = ((size_t)blockIdx.x * 256 + threadIdx.x) * 8;
    int b  = (int)(e >> 19);
    int ch = (int)(e & 511);
    int g  = ch >> 4;
    float m = stats[b * GGN + g], r = stats[512 + b * GGN + g];
    float4 x0 = *(const float4*)(x + e);
    float4 x1 = *(const float4*)(x + e + 4);
    float4 sq0 = *(const float4*)(gqs + ch), sq1 = *(const float4*)(gqs + ch + 4);
    float4 bq0 = *(const float4*)(gqb + ch), bq1 = *(const float4*)(gqb + ch + 4);
    float4 sk0 = *(const float4*)(gks + ch), sk1 = *(const float4*)(gks + ch + 4);
    float4 bk0 = *(const float4*)(gkb + ch), bk1 = *(const float4*)(gkb + ch + 4);
    float xs[8] = {x0.x,x0.y,x0.z,x0.w,x1.x,x1.y,x1.z,x1.w};
    float sqv[8] = {sq0.x,sq0.y,sq0.z,sq0.w,sq1.x,sq1.y,sq1.z,sq1.w};
    float bqv[8] = {bq0.x,bq0.y,bq0.z,bq0.w,bq1.x,bq1.y,bq1.z,bq1.w};
    float skv[8] = {sk0.x,sk0.y,sk0.z,sk0.w,sk1.x,sk1.y,sk1.z,sk1.w};
    float bkv[8] = {bk0.x,bk0.y,bk0.z,bk0.w,bk1.x,bk1.y,bk1.z,bk1.w};
    float q[8], k[8];
    #pragma unroll
    for (int j = 0; j < 8; j++){
      float nx = (xs[j] - m) * r;
      q[j] = (nx * sqv[j] + bqv[j]) * 0.18033688f; /* 0.125*log2(e) */
      k[j] = nx * skv[j] + bkv[j];
    }
    uint4 oq, ok;
    oq.x = pk2(q[0], q[1]); oq.y = pk2(q[2], q[3]);
    oq.z = pk2(q[4], q[5]); oq.w = pk2(q[6], q[7]);
    ok.x = pk2(k[0], k[1]); ok.y = pk2(k[2], k[3]);
    ok.z = pk2(k[4], k[5]); ok.w = pk2(k[6], k[7]);
    *(uint4*)(Xq + e)  = oq;
    *(uint4*)(Xkv + e) = ok;
  } else {
    size_t e = ((size_t)(blockIdx.x - 4096) * 256 + threadIdx.x) * 8;
    int b  = (int)(e >> 16);
    int rem = (int)(e & 65535);
    int l  = rem >> 9;
    int ch = rem & 511;
    uint4 o;
    if (l < LLT){
      int g = ch >> 4;
      float m = stats[1024 + b * GGN + g], r = stats[1536 + b * GGN + g];
      const float* src = t + ((size_t)b * LLT + l) * CCH + ch;
      float4 x0 = *(const float4*)src, x1 = *(const float4*)(src + 4);
      float4 s0 = *(const float4*)(gts + ch), s1 = *(const float4*)(gts + ch + 4);
      float4 b0 = *(const float4*)(gtb + ch), b1 = *(const float4*)(gtb + ch + 4);
      float xs[8] = {x0.x,x0.y,x0.z,x0.w,x1.x,x1.y,x1.z,x1.w};
      float sv[8] = {s0.x,s0.y,s0.z,s0.w,s1.x,s1.y,s1.z,s1.w};
      float bv[8] = {b0.x,b0.y,b0.z,b0.w,b1.x,b1.y,b1.z,b1.w};
      float w[8];
      #pragma unroll
      for (int j = 0; j < 8; j++) w[j] = (xs[j] - m) * r * sv[j] + bv[j];
      o.x = pk2(w[0], w[1]); o.y = pk2(w[2], w[3]);
      o.z = pk2(w[4], w[5]); o.w = pk2(w[6], w[7]);
    } else {
      o = make_uint4(0, 0, 0, 0);
    }
    *(uint4*)(Tn + e) = o;
  }
}

// -------- fused projections: self QKV (blocks 0-1535) + cross KV (1536-1791) -
// Self: 128x128-tile GEMM, m97-style global_load_lds staging (linear [64][64]
// LDS tiles, wave w DMAs tile w via 8x16B issues, 2 barriers/K-step).
// rt-fastest 1D decode keeps the 12 blocks sharing an A-panel on one XCD.
// Q/K epilogues: per-wave LDS transpose through the (dead) staging tile ->
// 8 vectorized uint4 stores per thread instead of 64 scalar 2B stores.
__global__ __launch_bounds__(256) void proj_all_mfma(
    const bf16* __restrict__ Xq, const bf16* __restrict__ Xkv,
    const bf16* __restrict__ Tn, const bf16* __restrict__ Wt,
    bf16* __restrict__ Qo, bf16* __restrict__ Ko, bf16* __restrict__ Vo)
{
  __shared__ alignas(16) char SHRAW[36864];
  const int tid  = threadIdx.x;
  const int wave = tid >> 6, lane = tid & 63;
  const int l16 = lane & 15, quad = lane >> 4;
  const int bx = blockIdx.x;

  if (bx < 1536){
    // ------------------------------ self QKV, gload_lds staging
    bf16 (*T)[64][64] = reinterpret_cast<bf16(*)[64][64]>(SHRAW);
    const int wr = wave >> 1, wc = wave & 1;
    const int ct = bx >> 7;             // 0..11
    const int rt = bx & 127;            // 0..127
    const int mat = ct >> 2;            // 0=Q, 1=K, 2=V
    const int cm0 = (ct & 3) * 128;
    const int b  = rt >> 3;
    const int n0 = (rt & 7) * 128;

    const bf16* A  = (mat == 0) ? Xq : Xkv;
    const bf16* Bw = Wt + (size_t)mat * CCH * CCH + (size_t)cm0 * CCH;

    f32x4 acc[4][4];
    #pragma unroll
    for (int rf = 0; rf < 4; rf++)
      #pragma unroll
      for (int cf = 0; cf < 4; cf++) acc[rf][cf] = (f32x4){0.f,0.f,0.f,0.f};

    // wave w stages tile w: 0/1 = A rows 0-63/64-127, 2/3 = B rows 0-63/64-127
    const int lrow = lane >> 3, lcol = (lane & 7) * 8;
    const bf16* srcbase = (wave < 2)
        ? A  + ((size_t)b * NN + n0 + wave * 64) * CCH
        : Bw + (size_t)((wave - 2) * 64) * CCH;

    for (int kt = 0; kt < 8; kt++){
      const int kc = kt * 64;
      #pragma unroll
      for (int c = 0; c < 8; c++){
        const bf16* g = srcbase + (size_t)(c * 8 + lrow) * CCH + kc + lcol;
        gload16(g, &T[wave][c * 8][0]);
      }
      __syncthreads();   // vmcnt(0) drain before barrier -> tile ready

      short8 af[4][2];
      #pragma unroll
      for (int rf = 0; rf < 4; rf++){
        af[rf][0] = *(const short8*)&T[wr][rf * 16 + l16][quad * 8];
        af[rf][1] = *(const short8*)&T[wr][rf * 16 + l16][32 + quad * 8];
      }
      #pragma unroll
      for (int cf = 0; cf < 4; cf++){
        const short8 b0 = *(const short8*)&T[2 + wc][cf * 16 + l16][quad * 8];
        const short8 b1 = *(const short8*)&T[2 + wc][cf * 16 + l16][32 + quad * 8];
        #pragma unroll
        for (int rf = 0; rf < 4; rf++){
          acc[rf][cf] = MFMA16(af[rf][0], b0, acc[rf][cf]);
          acc[rf][cf] = MFMA16(af[rf][1], b1, acc[rf][cf]);
        }
      }
      __syncthreads();   // protect overwrite of T by next K-step
    }

    const int h  = (cm0 + wc * 64) >> 6;
    const int nb = n0 + wr * 64;
    bf16 (*Tw)[64] = T[wave];   // this wave's staging tile, dead after k-loop

    if (mat < 2){
      // Q/K epilogue: per-wave transpose (rows n, cols d), then 8 uint4 stores
      bf16* Out = (mat == 0) ? Qo : Ko;
      const int stride = (mat == 0) ? NN : KVP;
      #pragma unroll
      for (int rf = 0; rf < 4; rf++)
        #pragma unroll
        for (int cf = 0; cf < 4; cf++)
          #pragma unroll
          for (int r = 0; r < 4; r++)
            Tw[rf * 16 + quad * 4 + r][cf * 16 + l16] =
                __float2bfloat16(acc[rf][cf][r]);
      const int rr = lane >> 2, cs = (lane & 3) * 16;
      #pragma unroll
      for (int k2 = 0; k2 < 4; k2++){
        const int row = rr + k2 * 16;
        bf16* od = Out + (((size_t)b * NHH + h) * stride + nb + row) * HDD + cs;
        *(uint4*)od       = *(const uint4*)&Tw[row][cs];
        *(uint4*)(od + 8) = *(const uint4*)&Tw[row][cs + 8];
      }
    } else {
      // V: per-wave transpose (rows d, cols n), then coalesced d-rows of Vt
      #pragma unroll
      for (int cf = 0; cf < 4; cf++)
        #pragma unroll
        for (int rf = 0; rf < 4; rf++)
          #pragma unroll
          for (int r = 0; r < 4; r++)
            Tw[cf * 16 + l16][rf * 16 + quad * 4 + r] =
                __float2bfloat16(acc[rf][cf][r]);
      __syncthreads();
      const int dl = lane >> 2, cseg = (lane & 3) * 16;
      #pragma unroll
      for (int k2 = 0; k2 < 4; k2++){
        const int d = dl + k2 * 16;
        bf16* vd = Vo + (((size_t)b * NHH + h) * HDD + d) * KVP + nb + cseg;
        *(uint4*)vd       = *(const uint4*)&Tw[d][cseg];
        *(uint4*)(vd + 8) = *(const uint4*)&Tw[d][cseg + 8];
      }
    }
  } else {
    // ------------------------------ cross KV (reg-staged, small)
    bf16 (*At)[72] = reinterpret_cast<bf16(*)[72]>(SHRAW);
    bf16 (*Bk)[72] = reinterpret_cast<bf16(*)[72]>(SHRAW + 64 * 72 * 2);
    bf16 (*Bv)[72] = reinterpret_cast<bf16(*)[72]>(SHRAW + 2 * 64 * 72 * 2);
    const int i  = bx - 1536;           // 0..255
    const int h  = i & 7;
    const int l0 = ((i >> 3) & 1) * 64;
    const int b  = i >> 4;

    const bf16* Wkc = Wt + 3 * (size_t)CCH * CCH;
    const bf16* Wvc = Wt + 4 * (size_t)CCH * CCH;

    f32x4 sk[4], sv[4];
    #pragma unroll
    for (int nt = 0; nt < 4; nt++){
      sk[nt] = (f32x4){0.f,0.f,0.f,0.f};
      sv[nt] = (f32x4){0.f,0.f,0.f,0.f};
    }

    const int sr = tid >> 2, sc = (tid & 3) * 16;
    const bf16* p_a  = Tn  + ((size_t)b * LPAD + l0 + sr) * CCH + sc;
    const bf16* p_bk = Wkc + (size_t)(h * 64 + sr) * CCH + sc;
    const bf16* p_bv = Wvc + (size_t)(h * 64 + sr) * CCH + sc;

    uint4 ra0 = *(const uint4*)p_a,   ra1 = *(const uint4*)(p_a + 8);
    uint4 rk0 = *(const uint4*)p_bk,  rk1 = *(const uint4*)(p_bk + 8);
    uint4 rv0 = *(const uint4*)p_bv,  rv1 = *(const uint4*)(p_bv + 8);

    for (int kt = 0; kt < 8; kt++){
      *(uint4*)&At[sr][sc]     = ra0;  *(uint4*)&At[sr][sc + 8] = ra1;
      *(uint4*)&Bk[sr][sc]     = rk0;  *(uint4*)&Bk[sr][sc + 8] = rk1;
      *(uint4*)&Bv[sr][sc]     = rv0;  *(uint4*)&Bv[sr][sc + 8] = rv1;
      if (kt < 7){
        const int k1 = (kt + 1) * 64;
        ra0 = *(const uint4*)(p_a + k1);   ra1 = *(const uint4*)(p_a + k1 + 8);
        rk0 = *(const uint4*)(p_bk + k1);  rk1 = *(const uint4*)(p_bk + k1 + 8);
        rv0 = *(const uint4*)(p_bv + k1);  rv1 = *(const uint4*)(p_bv + k1 + 8);
      }
      __syncthreads();

      const short8 a0 = *(const short8*)&At[wave * 16 + l16][quad * 8];
      const short8 a1 = *(const short8*)&At[wave * 16 + l16][32 + quad * 8];
      #pragma unroll
      for (int nt = 0; nt < 4; nt++){
        const short8 bk0 = *(const short8*)&Bk[nt * 16 + l16][quad * 8];
        const short8 bk1 = *(const short8*)&Bk[nt * 16 + l16][32 + quad * 8];
        sk[nt] = MFMA16(a0, bk0, sk[nt]);
        sk[nt] = MFMA16(a1, bk1, sk[nt]);
        const short8 bv0 = *(const short8*)&Bv[nt * 16 + l16][quad * 8];
        const short8 bv1 = *(const short8*)&Bv[nt * 16 + l16][32 + quad * 8];
        sv[nt] = MFMA16(a0, bv0, sv[nt]);
        sv[nt] = MFMA16(a1, bv1, sv[nt]);
      }
      __syncthreads();
    }

    #pragma unroll
    for (int r = 0; r < 4; r++){
      int kvrow = NN + l0 + wave * 16 + quad * 4 + r;
      bf16* kd = Ko + (((size_t)b * NHH + h) * KVP + kvrow) * HDD + l16;
      #pragma unroll
      for (int nt = 0; nt < 4; nt++)
        kd[nt * 16] = __float2bfloat16(sk[nt][r]);
    }

    __syncthreads();
    #pragma unroll
    for (int nt = 0; nt < 4; nt++)
      #pragma unroll
      for (int r = 0; r < 4; r++)
        Bk[nt * 16 + l16][wave * 16 + quad * 4 + r] = __float2bfloat16(sv[nt][r]);
    __syncthreads();
    {
      int d = tid >> 2, c = (tid & 3) * 16;
      bf16* vd = Vo + (((size_t)b * NHH + h) * HDD + d) * KVP + NN + l0 + c;
      *(uint4*)vd       = *(const uint4*)&Bk[d][c];
      *(uint4*)(vd + 8) = *(const uint4*)&Bk[d][c + 8];
    }
  }
}

// ------- MFMA flash attention, 32x32x16 path (UNCHANGED — control) ----------
__global__ __launch_bounds__(256, 4) void attn_mfma_kernel(
    const bf16* __restrict__ Q, const bf16* __restrict__ K,
    const bf16* __restrict__ Vt, const int* __restrict__ tmask,
    bf16* __restrict__ Ao)
{
  const int tid  = threadIdx.x;
  const int wave = tid >> 6;
  const int lane = tid & 63;
  const int l31  = lane & 31;
  const int hi   = lane >> 5;
  const int bx = blockIdx.x;
  const int q0 = (bx >> 7) * 128;
  const int g  = bx & 127;
  const int h  = g & 7;
  const int b  = g >> 3;

  __shared__ alignas(16) bf16 KV[2][2][64][72];

  const bf16* qp = Q + (((size_t)b * NHH + h) * NN + q0 + wave * 32 + l31) * HDD + hi * 8;
  short8 qf[4];
  qf[0] = *(const short8*)(qp);
  qf[1] = *(const short8*)(qp + 16);
  qf[2] = *(const short8*)(qp + 32);
  qf[3] = *(const short8*)(qp + 48);

  union { unsigned u[4]; short8 s8; } ones;
  ones.u[0] = 0x3F803F80u; ones.u[1] = 0x3F803F80u;
  ones.u[2] = 0x3F803F80u; ones.u[3] = 0x3F803F80u;

  f32x16 zf;
  #pragma unroll
  for (int i = 0; i < 16; i++) zf[i] = 0.f;

  f32x16 o_acc[2], l_acc;
  #pragma unroll
  for (int dt = 0; dt < 2; dt++)
    #pragma unroll
    for (int i = 0; i < 16; i++) o_acc[dt][i] = 0.f;
  #pragma unroll
  for (int i = 0; i < 16; i++) l_acc[i] = 0.f;

  const size_t kbase = ((size_t)b * NHH + h) * KVP;
  const size_t vbase = ((size_t)b * NHH + h) * (size_t)HDD * KVP;

  const int sr = tid >> 2;
  const int sc = (tid & 3) * 16;
  const bf16* kp = K  + (kbase + sr) * HDD + sc;
  const bf16* vp = Vt + vbase + (size_t)sr * KVP + sc;

  uint4 kr0 = *(const uint4*)kp, kr1 = *(const uint4*)(kp + 8);
  uint4 vr0 = *(const uint4*)vp, vr1 = *(const uint4*)(vp + 8);
  *(uint4*)&KV[0][0][sr][sc]     = kr0;
  *(uint4*)&KV[0][0][sr][sc + 8] = kr1;
  *(uint4*)&KV[0][1][sr][sc]     = vr0;
  *(uint4*)&KV[0][1][sr][sc + 8] = vr1;
  kr0 = *(const uint4*)(kp + 4096); kr1 = *(const uint4*)(kp + 4096 + 8);
  vr0 = *(const uint4*)(vp + 64);   vr1 = *(const uint4*)(vp + 64 + 8);
  __syncthreads();

  for (int kt = 0; kt < 18; kt++){
    const int cur = kt & 1;
    if (kt + 1 < 18){
      *(uint4*)&KV[cur ^ 1][0][sr][sc]     = kr0;
      *(uint4*)&KV[cur ^ 1][0][sr][sc + 8] = kr1;
      *(uint4*)&KV[cur ^ 1][1][sr][sc]     = vr0;
      *(uint4*)&KV[cur ^ 1][1][sr][sc + 8] = vr1;
    }
    if (kt + 2 < 18){
      const size_t ko = (size_t)(kt + 2) * 4096;
      const int    vo = (kt + 2) * 64;
      kr0 = *(const uint4*)(kp + ko); kr1 = *(const uint4*)(kp + ko + 8);
      vr0 = *(const uint4*)(vp + vo); vr1 = *(const uint4*)(vp + vo + 8);
    }

    const bf16 (*Ks)[72] = KV[cur][0];
    const bf16 (*Vs)[72] = KV[cur][1];
    const int kv0 = kt * 64;

    #pragma unroll
    for (int t = 0; t < 2; t++){
      const short8 kf0 = *(const short8*)&Ks[t * 32 + l31][hi * 8];
      const short8 kf1 = *(const short8*)&Ks[t * 32 + l31][16 + hi * 8];
      const short8 kf2 = *(const short8*)&Ks[t * 32 + l31][32 + hi * 8];
      const short8 kf3 = *(const short8*)&Ks[t * 32 + l31][48 + hi * 8];
      __builtin_amdgcn_s_setprio(1);
      f32x16 s = MFMA32(kf0, qf[0], zf);
      s = MFMA32(kf1, qf[1], s);
      s = MFMA32(kf2, qf[2], s);
      s = MFMA32(kf3, qf[3], s);
      __builtin_amdgcn_s_setprio(0);

      if (kv0 + 64 > NN){  // boundary tiles: text mask + KV padding
        #pragma unroll
        for (int r = 0; r < 16; r++){
          int idx = kv0 - NN + t * 32 + (r & 3) + 8 * (r >> 2) + 4 * hi;
          int ci = idx < LLT ? idx : LLT - 1;
          float rep = (idx < LLT)
                        ? (tmask[b * LLT + ci] > 0 ? 1e30f : -1e10f)
                        : -1e30f;
          s[r] = fminf(s[r], rep);
        }
      }

      #pragma unroll
      for (int r = 0; r < 16; r++) s[r] = fexp2(s[r]);

      unsigned w0 = pk2(s[0],  s[1]),  w1 = pk2(s[2],  s[3]);
      unsigned w2 = pk2(s[4],  s[5]),  w3 = pk2(s[6],  s[7]);
      unsigned w4 = pk2(s[8],  s[9]),  w5 = pk2(s[10], s[11]);
      unsigned w6 = pk2(s[12], s[13]), w7 = pk2(s[14], s[15]);
      pl32swap(w0, w2);
      pl32swap(w1, w3);
      pl32swap(w4, w6);
      pl32swap(w5, w7);
      union { unsigned u[4]; short8 s8; } pf0, pf1;
      pf0.u[0] = w0; pf0.u[1] = w1; pf0.u[2] = w2; pf0.u[3] = w3;
      pf1.u[0] = w4; pf1.u[1] = w5; pf1.u[2] = w6; pf1.u[3] = w7;

      const short8 vf00 = *(const short8*)&Vs[l31][t * 32 + hi * 8];
      const short8 vf01 = *(const short8*)&Vs[l31][t * 32 + 16 + hi * 8];
      const short8 vf10 = *(const short8*)&Vs[32 + l31][t * 32 + hi * 8];
      const short8 vf11 = *(const short8*)&Vs[32 + l31][t * 32 + 16 + hi * 8];

      __builtin_amdgcn_s_setprio(1);
      l_acc = MFMA32(pf0.s8, ones.s8, l_acc);
      l_acc = MFMA32(pf1.s8, ones.s8, l_acc);
      o_acc[0] = MFMA32(pf0.s8, vf00, o_acc[0]);
      o_acc[0] = MFMA32(pf1.s8, vf01, o_acc[0]);
      o_acc[1] = MFMA32(pf0.s8, vf10, o_acc[1]);
      o_acc[1] = MFMA32(pf1.s8, vf11, o_acc[1]);
      __builtin_amdgcn_s_setprio(0);
    }
    __syncthreads();
  }

  #pragma unroll
  for (int r = 0; r < 16; r++){
    const int ql = (r & 3) + 8 * (r >> 2) + 4 * hi;
    const float linv = 1.f / l_acc[r];
    const int n = q0 + wave * 32 + ql;
    bf16* dst = Ao + ((size_t)b * NN + n) * CCH + h * HDD + l31;
    dst[0]  = __float2bfloat16(o_acc[0][r] * linv);
    dst[32] = __float2bfloat16(o_acc[1][r] * linv);
  }
}

// ------------- output proj + residual, gload_lds-staged 128x128 GEMM --------
__global__ __launch_bounds__(256) void outproj_mfma(
    const bf16* __restrict__ A, const bf16* __restrict__ Wt,
    const float* __restrict__ resid, float* __restrict__ out)
{
  __shared__ alignas(16) bf16 T[4][64][64];
  const int tid  = threadIdx.x;
  const int wave = tid >> 6, lane = tid & 63;
  const int l16 = lane & 15, quad = lane >> 4;
  const int wr = wave >> 1, wc = wave & 1;
  const int bx = blockIdx.x;
  const int c0 = (bx >> 7) * 128;     // 0..511
  const int g0 = (bx & 127) * 128;    // 0..16383

  const bf16* Bw = Wt + (size_t)5 * CCH * CCH + (size_t)c0 * CCH;

  f32x4 acc[4][4];
  #pragma unroll
  for (int rf = 0; rf < 4; rf++)
    #pragma unroll
    for (int cf = 0; cf < 4; cf++) acc[rf][cf] = (f32x4){0.f,0.f,0.f,0.f};

  const int lrow = lane >> 3, lcol = (lane & 7) * 8;
  const bf16* srcbase = (wave < 2)
      ? A  + ((size_t)g0 + wave * 64) * CCH
      : Bw + (size_t)((wave - 2) * 64) * CCH;

  for (int kt = 0; kt < 8; kt++){
    const int kc = kt * 64;
    #pragma unroll
    for (int c = 0; c < 8; c++){
      const bf16* g = srcbase + (size_t)(c * 8 + lrow) * CCH + kc + lcol;
      gload16(g, &T[wave][c * 8][0]);
    }
    __syncthreads();

    short8 af[4][2];
    #pragma unroll
    for (int rf = 0; rf < 4; rf++){
      af[rf][0] = *(const short8*)&T[wr][rf * 16 + l16][quad * 8];
      af[rf][1] = *(const short8*)&T[wr][rf * 16 + l16][32 + quad * 8];
    }
    #pragma unroll
    for (int cf = 0; cf < 4; cf++){
      const short8 b0 = *(const short8*)&T[2 + wc][cf * 16 + l16][quad * 8];
      const short8 b1 = *(const short8*)&T[2 + wc][cf * 16 + l16][32 + quad * 8];
      #pragma unroll
      for (int rf = 0; rf < 4; rf++){
        acc[rf][cf] = MFMA16(af[rf][0], b0, acc[rf][cf]);
        acc[rf][cf] = MFMA16(af[rf][1], b1, acc[rf][cf]);
      }
    }
    __syncthreads();
  }

  #pragma unroll
  for (int rf = 0; rf < 4; rf++)
    #pragma unroll
    for (int r = 0; r < 4; r++){
      const size_t row = (size_t)g0 + wr * 64 + rf * 16 + quad * 4 + r;
      #pragma unroll
      for (int cf = 0; cf < 4; cf++){
        const int col = c0 + wc * 64 + cf * 16 + l16;
        out[row * CCH + col] = acc[rf][cf][r] + resid[row * CCH + col];
      }
    }
}

// --------------------------------------------------------------- launcher
extern "C" void kernel_launch(void* const* d_in, const int* in_sizes, int n_in,
                              void* d_out, int out_size, void* d_ws, size_t ws_size,
                              hipStream_t stream)
{
  const float* x     = (const float*)d_in[0];
  const float* txt   = (const float*)d_in[1];
  const int*   tmask = (const int*)d_in[2];
  const float* gqs   = (const float*)d_in[3];
  const float* gqb   = (const float*)d_in[4];
  const float* gks   = (const float*)d_in[5];
  const float* gkb   = (const float*)d_in[6];
  const float* gts   = (const float*)d_in[7];
  const float* gtb   = (const float*)d_in[8];
  const float* Wq    = (const float*)d_in[9];
  const float* Wks   = (const float*)d_in[10];
  const float* Wvs   = (const float*)d_in[11];
  const float* Wkc   = (const float*)d_in[12];
  const float* Wvc   = (const float*)d_in[13];
  const float* Wout  = (const float*)d_in[14];

  float* stats = (float*)d_ws;                            // 2048 floats
  bf16* WtAll = (bf16*)(stats + 2048);                    // 6 * 512 * 512
  bf16* Xq  = WtAll + (size_t)6 * CCH * CCH;
  bf16* Xkv = Xq  + (size_t)BB * NN * CCH;
  bf16* Tn  = Xkv + (size_t)BB * NN * CCH;
  bf16* Qw  = Tn  + (size_t)BB * LPAD * CCH;
  bf16* Kw  = Qw  + (size_t)BB * NHH * NN * HDD;
  bf16* Vw  = Kw  + (size_t)BB * NHH * KVP * HDD;         // [b,h,hd,kvp]
  bf16* Aw  = Xq;                                         // alias: Xq dead after proj

  pre_kernel<<<1408, 256, 0, stream>>>(
      x, txt, stats, Wq, Wks, Wvs, Wkc, Wvc, Wout, WtAll);
  norm_all_kernel<<<4608, 256, 0, stream>>>(
      x, txt, stats, gqs, gqb, gks, gkb, gts, gtb, Xq, Xkv, Tn);
  proj_all_mfma<<<1792, 256, 0, stream>>>(
      Xq, Xkv, Tn, WtAll, Qw, Kw, Vw);
  attn_mfma_kernel<<<1024, 256, 0, stream>>>(Qw, Kw, Vw, tmask, Aw);
  outproj_mfma<<<512, 256, 0, stream>>>(Aw, WtAll, x, (float*)d_out);
}

// Round 9
// 240.362 us; speedup vs baseline: 1.1035x; 1.0074x over previous
//
#include <hip/hip_runtime.h>
#include <hip/hip_bf16.h>

typedef __hip_bfloat16 bf16;
typedef __attribute__((ext_vector_type(8))) short short8;
typedef __attribute__((ext_vector_type(4))) float f32x4;
typedef __attribute__((ext_vector_type(16))) float f32x16;
#define MFMA16(a, b, c) __builtin_amdgcn_mfma_f32_16x16x32_bf16(a, b, c, 0, 0, 0)
#define MFMA32(a, b, c) __builtin_amdgcn_mfma_f32_32x32x16_bf16(a, b, c, 0, 0, 0)

#define BB   16
#define CCH  512
#define NN   1024
#define LLT  77
#define LPAD 128
#define NHH  8
#define HDD  64
#define GGN  32
#define NKV  1101   /* 1024 + 77 */
#define KVP  1152   /* 18 * 64, padded KV rows */

__device__ __forceinline__ unsigned short f2bu(float f){
  bf16 h = __float2bfloat16(f);
  return *reinterpret_cast<unsigned short*>(&h);
}

// single-instruction packed f32->bf16 (RNE)
__device__ __forceinline__ unsigned pk2(float lo, float hi){
  unsigned r;
  asm("v_cvt_pk_bf16_f32 %0, %1, %2" : "=v"(r) : "v"(lo), "v"(hi));
  return r;
}

// raw v_exp_f32 (exp2)
__device__ __forceinline__ float fexp2(float x){
  float r;
  asm("v_exp_f32 %0, %1" : "=v"(r) : "v"(x));
  return r;
}

// v_permlane32_swap_b32: new_a = {a.lo, b.lo}, new_b = {a.hi, b.hi}
__device__ __forceinline__ void pl32swap(unsigned &a, unsigned &b){
  asm("v_permlane32_swap_b32 %0, %1" : "+v"(a), "+v"(b));
}

// async global->LDS DMA, 16B per lane: lds dest = uniform base + lane*16,
// global src is per-lane.
__device__ __forceinline__ void gload16(const bf16* g, bf16* l){
  __builtin_amdgcn_global_load_lds(
      (const __attribute__((address_space(1))) unsigned int*)g,
      (__attribute__((address_space(3))) unsigned int*)l,
      16, 0, 0);
}

// --------------------- fused GN stats (1024 blocks) + weight prep (384) -----
__global__ __launch_bounds__(256) void pre_kernel(
    const float* __restrict__ ximg, const float* __restrict__ xtxt,
    float* __restrict__ stats,
    const float* __restrict__ W0, const float* __restrict__ W1,
    const float* __restrict__ W2, const float* __restrict__ W3,
    const float* __restrict__ W4, const float* __restrict__ W5,
    bf16* __restrict__ Wt)
{
  __shared__ float sh1[256], sh2[256];
  __shared__ alignas(16) float Ws[64][68];

  if (blockIdx.x < 1024){
    int isimg = blockIdx.x < 512;
    int bid = blockIdx.x & 511;
    int b = bid >> 5, g = bid & 31;
    int npos = isimg ? NN : LLT;
    const float* xb = (isimg ? ximg : xtxt) + (size_t)b * npos * CCH + g * 16;
    int tot4 = npos * 4;
    float s = 0.f, s2 = 0.f;
    for (int e = threadIdx.x; e < tot4; e += 256){
      int n = e >> 2, cq = (e & 3) * 4;
      float4 v = *(const float4*)(xb + (size_t)n * CCH + cq);
      s  += v.x + v.y + v.z + v.w;
      s2 += v.x * v.x + v.y * v.y + v.z * v.z + v.w * v.w;
    }
    sh1[threadIdx.x] = s; sh2[threadIdx.x] = s2;
    __syncthreads();
    for (int off = 128; off > 0; off >>= 1){
      if (threadIdx.x < off){
        sh1[threadIdx.x] += sh1[threadIdx.x + off];
        sh2[threadIdx.x] += sh2[threadIdx.x + off];
      }
      __syncthreads();
    }
    if (threadIdx.x == 0){
      float inv = 1.f / (float)(npos * 16);
      float m = sh1[0] * inv;
      float var = sh2[0] * inv - m * m;
      float* mu = stats + (isimg ? 0 : 1024);
      mu[bid] = m;
      mu[512 + bid] = rsqrtf(var + 1e-6f);
    }
  } else {
    int i = blockIdx.x - 1024;           // 0..383
    int wsel = i >> 6;                   // 0..5
    int rem  = i & 63;
    int n0 = (rem & 7) * 64, k0 = (rem >> 3) * 64;
    const float* W = wsel == 0 ? W0 : wsel == 1 ? W1 : wsel == 2 ? W2 :
                     wsel == 3 ? W3 : wsel == 4 ? W4 : W5;
    bf16* dst = Wt + (size_t)wsel * CCH * CCH;

    int r = threadIdx.x >> 2, c = (threadIdx.x & 3) * 16;
    const float* src = W + (size_t)(k0 + r) * CCH + n0 + c;
    *(float4*)&Ws[r][c]      = *(const float4*)(src);
    *(float4*)&Ws[r][c + 4]  = *(const float4*)(src + 4);
    *(float4*)&Ws[r][c + 8]  = *(const float4*)(src + 8);
    *(float4*)&Ws[r][c + 12] = *(const float4*)(src + 12);
    __syncthreads();

    int nr = threadIdx.x >> 2, kc = (threadIdx.x & 3) * 16;
    uint4 o0, o1;
    o0.x = pk2(Ws[kc + 0][nr],  Ws[kc + 1][nr]);
    o0.y = pk2(Ws[kc + 2][nr],  Ws[kc + 3][nr]);
    o0.z = pk2(Ws[kc + 4][nr],  Ws[kc + 5][nr]);
    o0.w = pk2(Ws[kc + 6][nr],  Ws[kc + 7][nr]);
    o1.x = pk2(Ws[kc + 8][nr],  Ws[kc + 9][nr]);
    o1.y = pk2(Ws[kc + 10][nr], Ws[kc + 11][nr]);
    o1.z = pk2(Ws[kc + 12][nr], Ws[kc + 13][nr]);
    o1.w = pk2(Ws[kc + 14][nr], Ws[kc + 15][nr]);
    bf16* d = dst + (size_t)(n0 + nr) * CCH + k0 + kc;
    *(uint4*)d = o0;
    *(uint4*)(d + 8) = o1;
  }
}

// ------------------------------------------------- norm img+text fused -> bf16
// Q side is pre-scaled by (1/sqrt(64)) * log2(e) so attention can use exp2.
__global__ __launch_bounds__(256) void norm_all_kernel(
    const float* __restrict__ x, const float* __restrict__ t,
    const float* __restrict__ stats,
    const float* __restrict__ gqs, const float* __restrict__ gqb,
    const float* __restrict__ gks, const float* __restrict__ gkb,
    const float* __restrict__ gts, const float* __restrict__ gtb,
    bf16* __restrict__ Xq, bf16* __restrict__ Xkv, bf16* __restrict__ Tn)
{
  if (blockIdx.x < 4096){
    size_t e = ((size_t)blockIdx.x * 256 + threadIdx.x) * 8;
    int b  = (int)(e >> 19);
    int ch = (int)(e & 511);
    int g  = ch >> 4;
    float m = stats[b * GGN + g], r = stats[512 + b * GGN + g];
    float4 x0 = *(const float4*)(x + e);
    float4 x1 = *(const float4*)(x + e + 4);
    float4 sq0 = *(const float4*)(gqs + ch), sq1 = *(const float4*)(gqs + ch + 4);
    float4 bq0 = *(const float4*)(gqb + ch), bq1 = *(const float4*)(gqb + ch + 4);
    float4 sk0 = *(const float4*)(gks + ch), sk1 = *(const float4*)(gks + ch + 4);
    float4 bk0 = *(const float4*)(gkb + ch), bk1 = *(const float4*)(gkb + ch + 4);
    float xs[8] = {x0.x,x0.y,x0.z,x0.w,x1.x,x1.y,x1.z,x1.w};
    float sqv[8] = {sq0.x,sq0.y,sq0.z,sq0.w,sq1.x,sq1.y,sq1.z,sq1.w};
    float bqv[8] = {bq0.x,bq0.y,bq0.z,bq0.w,bq1.x,bq1.y,bq1.z,bq1.w};
    float skv[8] = {sk0.x,sk0.y,sk0.z,sk0.w,sk1.x,sk1.y,sk1.z,sk1.w};
    float bkv[8] = {bk0.x,bk0.y,bk0.z,bk0.w,bk1.x,bk1.y,bk1.z,bk1.w};
    float q[8], k[8];
    #pragma unroll
    for (int j = 0; j < 8; j++){
      float nx = (xs[j] - m) * r;
      q[j] = (nx * sqv[j] + bqv[j]) * 0.18033688f; /* 0.125*log2(e) */
      k[j] = nx * skv[j] + bkv[j];
    }
    uint4 oq, ok;
    oq.x = pk2(q[0], q[1]); oq.y = pk2(q[2], q[3]);
    oq.z = pk2(q[4], q[5]); oq.w = pk2(q[6], q[7]);
    ok.x = pk2(k[0], k[1]); ok.y = pk2(k[2], k[3]);
    ok.z = pk2(k[4], k[5]); ok.w = pk2(k[6], k[7]);
    *(uint4*)(Xq + e)  = oq;
    *(uint4*)(Xkv + e) = ok;
  } else {
    size_t e = ((size_t)(blockIdx.x - 4096) * 256 + threadIdx.x) * 8;
    int b  = (int)(e >> 16);
    int rem = (int)(e & 65535);
    int l  = rem >> 9;
    int ch = rem & 511;
    uint4 o;
    if (l < LLT){
      int g = ch >> 4;
      float m = stats[1024 + b * GGN + g], r = stats[1536 + b * GGN + g];
      const float* src = t + ((size_t)b * LLT + l) * CCH + ch;
      float4 x0 = *(const float4*)src, x1 = *(const float4*)(src + 4);
      float4 s0 = *(const float4*)(gts + ch), s1 = *(const float4*)(gts + ch + 4);
      float4 b0 = *(const float4*)(gtb + ch), b1 = *(const float4*)(gtb + ch + 4);
      float xs[8] = {x0.x,x0.y,x0.z,x0.w,x1.x,x1.y,x1.z,x1.w};
      float sv[8] = {s0.x,s0.y,s0.z,s0.w,s1.x,s1.y,s1.z,s1.w};
      float bv[8] = {b0.x,b0.y,b0.z,b0.w,b1.x,b1.y,b1.z,b1.w};
      float w[8];
      #pragma unroll
      for (int j = 0; j < 8; j++) w[j] = (xs[j] - m) * r * sv[j] + bv[j];
      o.x = pk2(w[0], w[1]); o.y = pk2(w[2], w[3]);
      o.z = pk2(w[4], w[5]); o.w = pk2(w[6], w[7]);
    } else {
      o = make_uint4(0, 0, 0, 0);
    }
    *(uint4*)(Tn + e) = o;
  }
}

// -------- fused projections: self QKV (blocks 0-1535) + cross KV (1536-1791) -
// Self: 128x128-tile GEMM, m97-style global_load_lds staging (linear [64][64]
// LDS tiles, wave w DMAs tile w via 8x16B issues, 2 barriers/K-step).
// rt-fastest 1D decode keeps the 12 blocks sharing an A-panel on one XCD.
// Q/K epilogues: per-wave LDS transpose through the (dead) staging tile ->
// 8 vectorized uint4 stores per thread instead of 64 scalar 2B stores.
__global__ __launch_bounds__(256) void proj_all_mfma(
    const bf16* __restrict__ Xq, const bf16* __restrict__ Xkv,
    const bf16* __restrict__ Tn, const bf16* __restrict__ Wt,
    bf16* __restrict__ Qo, bf16* __restrict__ Ko, bf16* __restrict__ Vo)
{
  __shared__ alignas(16) char SHRAW[32768];
  const int tid  = threadIdx.x;
  const int wave = tid >> 6, lane = tid & 63;
  const int l16 = lane & 15, quad = lane >> 4;
  const int bx = blockIdx.x;

  if (bx < 1536){
    // ------------------------------ self QKV, gload_lds staging
    bf16 (*T)[64][64] = reinterpret_cast<bf16(*)[64][64]>(SHRAW);
    const int wr = wave >> 1, wc = wave & 1;
    const int ct = bx >> 7;             // 0..11
    const int rt = bx & 127;            // 0..127
    const int mat = ct >> 2;            // 0=Q, 1=K, 2=V
    const int cm0 = (ct & 3) * 128;
    const int b  = rt >> 3;
    const int n0 = (rt & 7) * 128;

    const bf16* A  = (mat == 0) ? Xq : Xkv;
    const bf16* Bw = Wt + (size_t)mat * CCH * CCH + (size_t)cm0 * CCH;

    f32x4 acc[4][4];
    #pragma unroll
    for (int rf = 0; rf < 4; rf++)
      #pragma unroll
      for (int cf = 0; cf < 4; cf++) acc[rf][cf] = (f32x4){0.f,0.f,0.f,0.f};

    // wave w stages tile w: 0/1 = A rows 0-63/64-127, 2/3 = B rows 0-63/64-127
    const int lrow = lane >> 3, lcol = (lane & 7) * 8;
    const bf16* srcbase = (wave < 2)
        ? A  + ((size_t)b * NN + n0 + wave * 64) * CCH
        : Bw + (size_t)((wave - 2) * 64) * CCH;

    for (int kt = 0; kt < 8; kt++){
      const int kc = kt * 64;
      #pragma unroll
      for (int c = 0; c < 8; c++){
        const bf16* g = srcbase + (size_t)(c * 8 + lrow) * CCH + kc + lcol;
        gload16(g, &T[wave][c * 8][0]);
      }
      __syncthreads();   // vmcnt(0) drain before barrier -> tile ready

      short8 af[4][2];
      #pragma unroll
      for (int rf = 0; rf < 4; rf++){
        af[rf][0] = *(const short8*)&T[wr][rf * 16 + l16][quad * 8];
        af[rf][1] = *(const short8*)&T[wr][rf * 16 + l16][32 + quad * 8];
      }
      #pragma unroll
      for (int cf = 0; cf < 4; cf++){
        const short8 b0 = *(const short8*)&T[2 + wc][cf * 16 + l16][quad * 8];
        const short8 b1 = *(const short8*)&T[2 + wc][cf * 16 + l16][32 + quad * 8];
        #pragma unroll
        for (int rf = 0; rf < 4; rf++){
          acc[rf][cf] = MFMA16(af[rf][0], b0, acc[rf][cf]);
          acc[rf][cf] = MFMA16(af[rf][1], b1, acc[rf][cf]);
        }
      }
      __syncthreads();   // protect overwrite of T by next K-step
    }

    const int h  = (cm0 + wc * 64) >> 6;
    const int nb = n0 + wr * 64;
    bf16 (*Tw)[64] = T[wave];   // this wave's staging tile, dead after k-loop

    if (mat < 2){
      // Q/K epilogue: per-wave transpose (rows n, cols d), then 8 uint4 stores
      bf16* Out = (mat == 0) ? Qo : Ko;
      const int stride = (mat == 0) ? NN : KVP;
      #pragma unroll
      for (int rf = 0; rf < 4; rf++)
        #pragma unroll
        for (int cf = 0; cf < 4; cf++)
          #pragma unroll
          for (int r = 0; r < 4; r++)
            Tw[rf * 16 + quad * 4 + r][cf * 16 + l16] =
                __float2bfloat16(acc[rf][cf][r]);
      const int rr = lane >> 2, cs = (lane & 3) * 16;
      #pragma unroll
      for (int k2 = 0; k2 < 4; k2++){
        const int row = rr + k2 * 16;
        bf16* od = Out + (((size_t)b * NHH + h) * stride + nb + row) * HDD + cs;
        *(uint4*)od       = *(const uint4*)&Tw[row][cs];
        *(uint4*)(od + 8) = *(const uint4*)&Tw[row][cs + 8];
      }
    } else {
      // V: per-wave transpose (rows d, cols n), then coalesced d-rows of Vt
      #pragma unroll
      for (int cf = 0; cf < 4; cf++)
        #pragma unroll
        for (int rf = 0; rf < 4; rf++)
          #pragma unroll
          for (int r = 0; r < 4; r++)
            Tw[cf * 16 + l16][rf * 16 + quad * 4 + r] =
                __float2bfloat16(acc[rf][cf][r]);
      __syncthreads();
      const int dl = lane >> 2, cseg = (lane & 3) * 16;
      #pragma unroll
      for (int k2 = 0; k2 < 4; k2++){
        const int d = dl + k2 * 16;
        bf16* vd = Vo + (((size_t)b * NHH + h) * HDD + d) * KVP + nb + cseg;
        *(uint4*)vd       = *(const uint4*)&Tw[d][cseg];
        *(uint4*)(vd + 8) = *(const uint4*)&Tw[d][cseg + 8];
      }
    }
  } else {
    // ------------------------------ cross KV (reg-staged, small)
    bf16 (*At)[72] = reinterpret_cast<bf16(*)[72]>(SHRAW);
    bf16 (*Bk)[72] = reinterpret_cast<bf16(*)[72]>(SHRAW + 64 * 72 * 2);
    bf16 (*Bv)[72] = reinterpret_cast<bf16(*)[72]>(SHRAW + 2 * 64 * 72 * 2);
    const int i  = bx - 1536;           // 0..255
    const int h  = i & 7;
    const int l0 = ((i >> 3) & 1) * 64;
    const int b  = i >> 4;

    const bf16* Wkc = Wt + 3 * (size_t)CCH * CCH;
    const bf16* Wvc = Wt + 4 * (size_t)CCH * CCH;

    f32x4 sk[4], sv[4];
    #pragma unroll
    for (int nt = 0; nt < 4; nt++){
      sk[nt] = (f32x4){0.f,0.f,0.f,0.f};
      sv[nt] = (f32x4){0.f,0.f,0.f,0.f};
    }

    const int sr = tid >> 2, sc = (tid & 3) * 16;
    const bf16* p_a  = Tn  + ((size_t)b * LPAD + l0 + sr) * CCH + sc;
    const bf16* p_bk = Wkc + (size_t)(h * 64 + sr) * CCH + sc;
    const bf16* p_bv = Wvc + (size_t)(h * 64 + sr) * CCH + sc;

    uint4 ra0 = *(const uint4*)p_a,   ra1 = *(const uint4*)(p_a + 8);
    uint4 rk0 = *(const uint4*)p_bk,  rk1 = *(const uint4*)(p_bk + 8);
    uint4 rv0 = *(const uint4*)p_bv,  rv1 = *(const uint4*)(p_bv + 8);

    for (int kt = 0; kt < 8; kt++){
      *(uint4*)&At[sr][sc]     = ra0;  *(uint4*)&At[sr][sc + 8] = ra1;
      *(uint4*)&Bk[sr][sc]     = rk0;  *(uint4*)&Bk[sr][sc + 8] = rk1;
      *(uint4*)&Bv[sr][sc]     = rv0;  *(uint4*)&Bv[sr][sc + 8] = rv1;
      if (kt < 7){
        const int k1 = (kt + 1) * 64;
        ra0 = *(const uint4*)(p_a + k1);   ra1 = *(const uint4*)(p_a + k1 + 8);
        rk0 = *(const uint4*)(p_bk + k1);  rk1 = *(const uint4*)(p_bk + k1 + 8);
        rv0 = *(const uint4*)(p_bv + k1);  rv1 = *(const uint4*)(p_bv + k1 + 8);
      }
      __syncthreads();

      const short8 a0 = *(const short8*)&At[wave * 16 + l16][quad * 8];
      const short8 a1 = *(const short8*)&At[wave * 16 + l16][32 + quad * 8];
      #pragma unroll
      for (int nt = 0; nt < 4; nt++){
        const short8 bk0 = *(const short8*)&Bk[nt * 16 + l16][quad * 8];
        const short8 bk1 = *(const short8*)&Bk[nt * 16 + l16][32 + quad * 8];
        sk[nt] = MFMA16(a0, bk0, sk[nt]);
        sk[nt] = MFMA16(a1, bk1, sk[nt]);
        const short8 bv0 = *(const short8*)&Bv[nt * 16 + l16][quad * 8];
        const short8 bv1 = *(const short8*)&Bv[nt * 16 + l16][32 + quad * 8];
        sv[nt] = MFMA16(a0, bv0, sv[nt]);
        sv[nt] = MFMA16(a1, bv1, sv[nt]);
      }
      __syncthreads();
    }

    #pragma unroll
    for (int r = 0; r < 4; r++){
      int kvrow = NN + l0 + wave * 16 + quad * 4 + r;
      bf16* kd = Ko + (((size_t)b * NHH + h) * KVP + kvrow) * HDD + l16;
      #pragma unroll
      for (int nt = 0; nt < 4; nt++)
        kd[nt * 16] = __float2bfloat16(sk[nt][r]);
    }

    __syncthreads();
    #pragma unroll
    for (int nt = 0; nt < 4; nt++)
      #pragma unroll
      for (int r = 0; r < 4; r++)
        Bk[nt * 16 + l16][wave * 16 + quad * 4 + r] = __float2bfloat16(sv[nt][r]);
    __syncthreads();
    {
      int d = tid >> 2, c = (tid & 3) * 16;
      bf16* vd = Vo + (((size_t)b * NHH + h) * HDD + d) * KVP + NN + l0 + c;
      *(uint4*)vd       = *(const uint4*)&Bk[d][c];
      *(uint4*)(vd + 8) = *(const uint4*)&Bk[d][c + 8];
    }
  }
}

// ------- MFMA flash attention, 32x32x16 path (UNCHANGED — control) ----------
__global__ __launch_bounds__(256, 4) void attn_mfma_kernel(
    const bf16* __restrict__ Q, const bf16* __restrict__ K,
    const bf16* __restrict__ Vt, const int* __restrict__ tmask,
    bf16* __restrict__ Ao)
{
  const int tid  = threadIdx.x;
  const int wave = tid >> 6;
  const int lane = tid & 63;
  const int l31  = lane & 31;
  const int hi   = lane >> 5;
  const int bx = blockIdx.x;
  const int q0 = (bx >> 7) * 128;
  const int g  = bx & 127;
  const int h  = g & 7;
  const int b  = g >> 3;

  __shared__ alignas(16) bf16 KV[2][2][64][72];

  const bf16* qp = Q + (((size_t)b * NHH + h) * NN + q0 + wave * 32 + l31) * HDD + hi * 8;
  short8 qf[4];
  qf[0] = *(const short8*)(qp);
  qf[1] = *(const short8*)(qp + 16);
  qf[2] = *(const short8*)(qp + 32);
  qf[3] = *(const short8*)(qp + 48);

  union { unsigned u[4]; short8 s8; } ones;
  ones.u[0] = 0x3F803F80u; ones.u[1] = 0x3F803F80u;
  ones.u[2] = 0x3F803F80u; ones.u[3] = 0x3F803F80u;

  f32x16 zf;
  #pragma unroll
  for (int i = 0; i < 16; i++) zf[i] = 0.f;

  f32x16 o_acc[2], l_acc;
  #pragma unroll
  for (int dt = 0; dt < 2; dt++)
    #pragma unroll
    for (int i = 0; i < 16; i++) o_acc[dt][i] = 0.f;
  #pragma unroll
  for (int i = 0; i < 16; i++) l_acc[i] = 0.f;

  const size_t kbase = ((size_t)b * NHH + h) * KVP;
  const size_t vbase = ((size_t)b * NHH + h) * (size_t)HDD * KVP;

  const int sr = tid >> 2;
  const int sc = (tid & 3) * 16;
  const bf16* kp = K  + (kbase + sr) * HDD + sc;
  const bf16* vp = Vt + vbase + (size_t)sr * KVP + sc;

  uint4 kr0 = *(const uint4*)kp, kr1 = *(const uint4*)(kp + 8);
  uint4 vr0 = *(const uint4*)vp, vr1 = *(const uint4*)(vp + 8);
  *(uint4*)&KV[0][0][sr][sc]     = kr0;
  *(uint4*)&KV[0][0][sr][sc + 8] = kr1;
  *(uint4*)&KV[0][1][sr][sc]     = vr0;
  *(uint4*)&KV[0][1][sr][sc + 8] = vr1;
  kr0 = *(const uint4*)(kp + 4096); kr1 = *(const uint4*)(kp + 4096 + 8);
  vr0 = *(const uint4*)(vp + 64);   vr1 = *(const uint4*)(vp + 64 + 8);
  __syncthreads();

  for (int kt = 0; kt < 18; kt++){
    const int cur = kt & 1;
    if (kt + 1 < 18){
      *(uint4*)&KV[cur ^ 1][0][sr][sc]     = kr0;
      *(uint4*)&KV[cur ^ 1][0][sr][sc + 8] = kr1;
      *(uint4*)&KV[cur ^ 1][1][sr][sc]     = vr0;
      *(uint4*)&KV[cur ^ 1][1][sr][sc + 8] = vr1;
    }
    if (kt + 2 < 18){
      const size_t ko = (size_t)(kt + 2) * 4096;
      const int    vo = (kt + 2) * 64;
      kr0 = *(const uint4*)(kp + ko); kr1 = *(const uint4*)(kp + ko + 8);
      vr0 = *(const uint4*)(vp + vo); vr1 = *(const uint4*)(vp + vo + 8);
    }

    const bf16 (*Ks)[72] = KV[cur][0];
    const bf16 (*Vs)[72] = KV[cur][1];
    const int kv0 = kt * 64;

    #pragma unroll
    for (int t = 0; t < 2; t++){
      const short8 kf0 = *(const short8*)&Ks[t * 32 + l31][hi * 8];
      const short8 kf1 = *(const short8*)&Ks[t * 32 + l31][16 + hi * 8];
      const short8 kf2 = *(const short8*)&Ks[t * 32 + l31][32 + hi * 8];
      const short8 kf3 = *(const short8*)&Ks[t * 32 + l31][48 + hi * 8];
      __builtin_amdgcn_s_setprio(1);
      f32x16 s = MFMA32(kf0, qf[0], zf);
      s = MFMA32(kf1, qf[1], s);
      s = MFMA32(kf2, qf[2], s);
      s = MFMA32(kf3, qf[3], s);
      __builtin_amdgcn_s_setprio(0);

      if (kv0 + 64 > NN){  // boundary tiles: text mask + KV padding
        #pragma unroll
        for (int r = 0; r < 16; r++){
          int idx = kv0 - NN + t * 32 + (r & 3) + 8 * (r >> 2) + 4 * hi;
          int ci = idx < LLT ? idx : LLT - 1;
          float rep = (idx < LLT)
                        ? (tmask[b * LLT + ci] > 0 ? 1e30f : -1e10f)
                        : -1e30f;
          s[r] = fminf(s[r], rep);
        }
      }

      #pragma unroll
      for (int r = 0; r < 16; r++) s[r] = fexp2(s[r]);

      unsigned w0 = pk2(s[0],  s[1]),  w1 = pk2(s[2],  s[3]);
      unsigned w2 = pk2(s[4],  s[5]),  w3 = pk2(s[6],  s[7]);
      unsigned w4 = pk2(s[8],  s[9]),  w5 = pk2(s[10], s[11]);
      unsigned w6 = pk2(s[12], s[13]), w7 = pk2(s[14], s[15]);
      pl32swap(w0, w2);
      pl32swap(w1, w3);
      pl32swap(w4, w6);
      pl32swap(w5, w7);
      union { unsigned u[4]; short8 s8; } pf0, pf1;
      pf0.u[0] = w0; pf0.u[1] = w1; pf0.u[2] = w2; pf0.u[3] = w3;
      pf1.u[0] = w4; pf1.u[1] = w5; pf1.u[2] = w6; pf1.u[3] = w7;

      const short8 vf00 = *(const short8*)&Vs[l31][t * 32 + hi * 8];
      const short8 vf01 = *(const short8*)&Vs[l31][t * 32 + 16 + hi * 8];
      const short8 vf10 = *(const short8*)&Vs[32 + l31][t * 32 + hi * 8];
      const short8 vf11 = *(const short8*)&Vs[32 + l31][t * 32 + 16 + hi * 8];

      __builtin_amdgcn_s_setprio(1);
      l_acc = MFMA32(pf0.s8, ones.s8, l_acc);
      l_acc = MFMA32(pf1.s8, ones.s8, l_acc);
      o_acc[0] = MFMA32(pf0.s8, vf00, o_acc[0]);
      o_acc[0] = MFMA32(pf1.s8, vf01, o_acc[0]);
      o_acc[1] = MFMA32(pf0.s8, vf10, o_acc[1]);
      o_acc[1] = MFMA32(pf1.s8, vf11, o_acc[1]);
      __builtin_amdgcn_s_setprio(0);
    }
    __syncthreads();
  }

  #pragma unroll
  for (int r = 0; r < 16; r++){
    const int ql = (r & 3) + 8 * (r >> 2) + 4 * hi;
    const float linv = 1.f / l_acc[r];
    const int n = q0 + wave * 32 + ql;
    bf16* dst = Ao + ((size_t)b * NN + n) * CCH + h * HDD + l31;
    dst[0]  = __float2bfloat16(o_acc[0][r] * linv);
    dst[32] = __float2bfloat16(o_acc[1][r] * linv);
  }
}

// ------------- output proj + residual, gload_lds-staged 128x128 GEMM --------
// Epilogue: per-wave f32 LDS transpose (f32[32][68], pad-68: writes 2-way=free,
// reads spread 8-even=free), two 32-row halves -> float4 resid+store.
// 128 scalar VMEM ops/thread -> 32 vector VMEM ops/thread, fully coalesced.
__global__ __launch_bounds__(256) void outproj_mfma(
    const bf16* __restrict__ A, const bf16* __restrict__ Wt,
    const float* __restrict__ resid, float* __restrict__ out)
{
  __shared__ alignas(16) char SH[36864];
  bf16 (*T)[64][64] = reinterpret_cast<bf16(*)[64][64]>(SH);
  const int tid  = threadIdx.x;
  const int wave = tid >> 6, lane = tid & 63;
  const int l16 = lane & 15, quad = lane >> 4;
  const int wr = wave >> 1, wc = wave & 1;
  const int bx = blockIdx.x;
  const int c0 = (bx >> 7) * 128;     // 0..511
  const int g0 = (bx & 127) * 128;    // 0..16383

  const bf16* Bw = Wt + (size_t)5 * CCH * CCH + (size_t)c0 * CCH;

  f32x4 acc[4][4];
  #pragma unroll
  for (int rf = 0; rf < 4; rf++)
    #pragma unroll
    for (int cf = 0; cf < 4; cf++) acc[rf][cf] = (f32x4){0.f,0.f,0.f,0.f};

  const int lrow = lane >> 3, lcol = (lane & 7) * 8;
  const bf16* srcbase = (wave < 2)
      ? A  + ((size_t)g0 + wave * 64) * CCH
      : Bw + (size_t)((wave - 2) * 64) * CCH;

  for (int kt = 0; kt < 8; kt++){
    const int kc = kt * 64;
    #pragma unroll
    for (int c = 0; c < 8; c++){
      const bf16* g = srcbase + (size_t)(c * 8 + lrow) * CCH + kc + lcol;
      gload16(g, &T[wave][c * 8][0]);
    }
    __syncthreads();

    short8 af[4][2];
    #pragma unroll
    for (int rf = 0; rf < 4; rf++){
      af[rf][0] = *(const short8*)&T[wr][rf * 16 + l16][quad * 8];
      af[rf][1] = *(const short8*)&T[wr][rf * 16 + l16][32 + quad * 8];
    }
    #pragma unroll
    for (int cf = 0; cf < 4; cf++){
      const short8 b0 = *(const short8*)&T[2 + wc][cf * 16 + l16][quad * 8];
      const short8 b1 = *(const short8*)&T[2 + wc][cf * 16 + l16][32 + quad * 8];
      #pragma unroll
      for (int rf = 0; rf < 4; rf++){
        acc[rf][cf] = MFMA16(af[rf][0], b0, acc[rf][cf]);
        acc[rf][cf] = MFMA16(af[rf][1], b1, acc[rf][cf]);
      }
    }
    __syncthreads();
  }

  // -------- vectorized epilogue (per-wave region SH + wave*8704, f32[32][68])
  float (*Tf)[68] = reinterpret_cast<float(*)[68]>(SH + wave * 8704);
  const int cg = (lane & 15) * 4;     // float4-granular col within 64
  #pragma unroll
  for (int hf = 0; hf < 2; hf++){
    #pragma unroll
    for (int rf = 0; rf < 2; rf++)
      #pragma unroll
      for (int cf = 0; cf < 4; cf++)
        #pragma unroll
        for (int r = 0; r < 4; r++)
          Tf[rf * 16 + quad * 4 + r][cf * 16 + l16] = acc[hf * 2 + rf][cf][r];
    // intra-wave RAW through same pointer: compiler orders via lgkmcnt
    #pragma unroll
    for (int k = 0; k < 8; k++){
      const int row32 = k * 4 + quad;
      const size_t grow = (size_t)g0 + wr * 64 + hf * 32 + row32;
      const int gcol = c0 + wc * 64 + cg;
      float4 v  = *(const float4*)&Tf[row32][cg];
      float4 rz = *(const float4*)&resid[grow * CCH + gcol];
      v.x += rz.x; v.y += rz.y; v.z += rz.z; v.w += rz.w;
      *(float4*)&out[grow * CCH + gcol] = v;
    }
    if (hf == 0){
      // WAR: all hf=0 reads drained before hf=1 overwrites the same rows
      asm volatile("s_waitcnt lgkmcnt(0)" ::: "memory");
      __builtin_amdgcn_sched_barrier(0);
    }
  }
}

// --------------------------------------------------------------- launcher
extern "C" void kernel_launch(void* const* d_in, const int* in_sizes, int n_in,
                              void* d_out, int out_size, void* d_ws, size_t ws_size,
                              hipStream_t stream)
{
  const float* x     = (const float*)d_in[0];
  const float* txt   = (const float*)d_in[1];
  const int*   tmask = (const int*)d_in[2];
  const float* gqs   = (const float*)d_in[3];
  const float* gqb   = (const float*)d_in[4];
  const float* gks   = (const float*)d_in[5];
  const float* gkb   = (const float*)d_in[6];
  const float* gts   = (const float*)d_in[7];
  const float* gtb   = (const float*)d_in[8];
  const float* Wq    = (const float*)d_in[9];
  const float* Wks   = (const float*)d_in[10];
  const float* Wvs   = (const float*)d_in[11];
  const float* Wkc   = (const float*)d_in[12];
  const float* Wvc   = (const float*)d_in[13];
  const float* Wout  = (const float*)d_in[14];

  float* stats = (float*)d_ws;                            // 2048 floats
  bf16* WtAll = (bf16*)(stats + 2048);                    // 6 * 512 * 512
  bf16* Xq  = WtAll + (size_t)6 * CCH * CCH;
  bf16* Xkv = Xq  + (size_t)BB * NN * CCH;
  bf16* Tn  = Xkv + (size_t)BB * NN * CCH;
  bf16* Qw  = Tn  + (size_t)BB * LPAD * CCH;
  bf16* Kw  = Qw  + (size_t)BB * NHH * NN * HDD;
  bf16* Vw  = Kw  + (size_t)BB * NHH * KVP * HDD;         // [b,h,hd,kvp]
  bf16* Aw  = Xq;                                         // alias: Xq dead after proj

  pre_kernel<<<1408, 256, 0, stream>>>(
      x, txt, stats, Wq, Wks, Wvs, Wkc, Wvc, Wout, WtAll);
  norm_all_kernel<<<4608, 256, 0, stream>>>(
      x, txt, stats, gqs, gqb, gks, gkb, gts, gtb, Xq, Xkv, Tn);
  proj_all_mfma<<<1792, 256, 0, stream>>>(
      Xq, Xkv, Tn, WtAll, Qw, Kw, Vw);
  attn_mfma_kernel<<<1024, 256, 0, stream>>>(Qw, Kw, Vw, tmask, Aw);
  outproj_mfma<<<512, 256, 0, stream>>>(Aw, WtAll, x, (float*)d_out);
}